// Round 1
// baseline (367.394 us; speedup 1.0000x reference)
//
#include <hip/hip_runtime.h>
#include <math.h>

#define BG    128                      // graphs (B)
#define NN    40                       // nodes per graph
#define AK    32                       // K (mixture comps)
#define ZD    32                       // Z latent dim
#define HIDN  256                      // HID
#define ETAD  64                       // ETA
#define NATOM 24
#define NBOND 5
#define NA    (BG*NN)                  // 5120 nodes
#define EPG   (NN*(NN-1)/2)            // 780 edges per graph
#define NE    (BG*EPG)                 // 99840 edges

// ---------------- class head ----------------
__global__ void k_class_h1(const float* __restrict__ eta, const float* __restrict__ cw1,
                           const float* __restrict__ cb1, float* __restrict__ h1) {
    __shared__ float es[ETAD];
    int r = blockIdx.x, c = threadIdx.x;
    if (c < ETAD) es[c] = eta[r*ETAD + c];
    __syncthreads();
    float acc = cb1[c];
#pragma unroll
    for (int a = 0; a < ETAD; ++a) acc += es[a] * cw1[a*HIDN + c];
    h1[r*HIDN + c] = acc;
}

__global__ void k_class_stats(const float* __restrict__ h1, float* __restrict__ mean,
                              float* __restrict__ var) {
    int c = threadIdx.x;
    float s = 0.f;
    for (int r = 0; r < BG; ++r) s += h1[r*HIDN + c];
    float m = s / (float)BG;
    float v = 0.f;
    for (int r = 0; r < BG; ++r) { float d = h1[r*HIDN + c] - m; v += d*d; }
    mean[c] = m;
    var[c]  = v / (float)BG;
}

__global__ void k_class_out(const float* __restrict__ h1, const float* __restrict__ mean,
                            const float* __restrict__ var, const float* __restrict__ cg,
                            const float* __restrict__ cbe, const float* __restrict__ ca,
                            const float* __restrict__ cw2, const float* __restrict__ cb2,
                            float* __restrict__ log_pi) {
    __shared__ float p[HIDN];
    __shared__ float o[AK];
    int r = blockIdx.x, t = threadIdx.x;
    float a = ca[0];
    {
        float x = h1[r*HIDN + t];
        float m = mean[t], v = var[t];
        float xn = (x - m) * (1.0f/sqrtf(v + 1e-5f)) * cg[t] + cbe[t];
        p[t] = xn >= 0.f ? xn : a*xn;
    }
    __syncthreads();
    if (t < AK) {
        float acc = cb2[t];
        for (int c = 0; c < HIDN; ++c) acc += p[c] * cw2[c*AK + t];
        o[t] = acc;
    }
    __syncthreads();
    if (t < AK) {
        float m = -INFINITY;
#pragma unroll
        for (int k = 0; k < AK; ++k) m = fmaxf(m, o[k]);
        float S = 0.f;
#pragma unroll
        for (int k = 0; k < AK; ++k) S += expf(o[k] - m);
        log_pi[r*AK + t] = o[t] - m - logf(S);
    }
}

// ---------------- gumbel + latent z ----------------
__global__ void k_node_z(const float* __restrict__ log_pi, const float* __restrict__ gum,
                         const float* __restrict__ noise, const float* __restrict__ cm,
                         const float* __restrict__ cls, float* __restrict__ z) {
    int n = blockIdx.x*blockDim.x + threadIdx.x;
    if (n >= NA) return;
    int g = n / NN;
    float x[AK];
    float m = -INFINITY;
#pragma unroll
    for (int k = 0; k < AK; ++k) {
        float u  = gum[n*AK + k];
        float gk = -logf(-logf(u));
        float xk = log_pi[g*AK + k] + gk;     // TAU == 1.0
        x[k] = xk; m = fmaxf(m, xk);
    }
    float S = 0.f;
#pragma unroll
    for (int k = 0; k < AK; ++k) { float e = expf(x[k] - m); x[k] = e; S += e; }
    float best = -INFINITY; int am = 0;
#pragma unroll
    for (int k = 0; k < AK; ++k) { float s = x[k] / S; if (s > best) { best = s; am = k; } }
    float cam = (1.0f - best) + best;          // exact fp replication of y_hard - sg(y) + y
#pragma unroll
    for (int j = 0; j < ZD; ++j) {
        float ls = cam * cls[am*ZD + j];
        ls = fminf(fmaxf(ls, -20.0f), 30.0f);
        z[n*ZD + j] = noise[n*ZD + j] * expf(ls) + cam * cm[am*ZD + j];
    }
}

// ---------------- atom MLP ----------------
#define AROWS 20
__global__ void k_atom_h(const float* __restrict__ z, const float* __restrict__ aw1,
                         const float* __restrict__ ab1, float* __restrict__ h,
                         float* __restrict__ stats) {
    __shared__ float zs[AROWS*ZD];
    int r0 = blockIdx.x * AROWS;
    int t = threadIdx.x;
    for (int i = t; i < AROWS*ZD; i += HIDN) zs[i] = z[r0*ZD + i];
    __syncthreads();
    float b = ab1[t], s = 0.f, ss = 0.f;
    for (int r = 0; r < AROWS; ++r) {
        float acc = b;
#pragma unroll
        for (int a = 0; a < ZD; ++a) acc += zs[r*ZD + a] * aw1[a*HIDN + t];
        h[(r0+r)*HIDN + t] = acc;
        s += acc; ss += acc*acc;
    }
    atomicAdd(&stats[t], s);
    atomicAdd(&stats[HIDN + t], ss);
}

#define ORROWS 8
#define PSTR   260    // padded LDS row stride (bank-conflict-free: stride%32==4)
__global__ void k_atom_out(const float* __restrict__ h, const float* __restrict__ stats,
                           const float* __restrict__ ag, const float* __restrict__ abe,
                           const float* __restrict__ aa, const float* __restrict__ aw2,
                           const float* __restrict__ ab2, float* __restrict__ out) {
    __shared__ float p[ORROWS*PSTR];
    int r0 = blockIdx.x * ORROWS;
    int t = threadIdx.x;
    float a = aa[0];
    const float invA = 1.0f / (float)NA;
    for (int idx = t; idx < ORROWS*HIDN; idx += HIDN) {
        int r = idx >> 8, c = idx & 255;
        float x = h[(r0+r)*HIDN + c];
        float m = stats[c] * invA;
        float v = stats[HIDN + c] * invA - m*m;
        float xn = (x - m) * (1.0f/sqrtf(v + 1e-5f)) * ag[c] + abe[c];
        p[r*PSTR + c] = xn >= 0.f ? xn : a*xn;
    }
    __syncthreads();
    if (t < ORROWS*NATOM) {
        int r = t / NATOM, k = t % NATOM;
        float acc = ab2[k];
        for (int c = 0; c < HIDN; ++c) acc += p[r*PSTR + c] * aw2[c*NATOM + k];
        out[(r0+r)*NATOM + k] = acc;
    }
}

// ---------------- bond pipeline ----------------
__global__ void k_wm(const float* __restrict__ bm, float* __restrict__ wm) {
    int idx = blockIdx.x*256 + threadIdx.x;   // 32768 total
    int d = idx >> 10, ab = idx & 1023, a = ab >> 5, b = ab & 31;
    wm[idx] = 0.5f * (bm[idx] + bm[d*1024 + b*32 + a]);
}

#define TSTR 33   // padded T row stride
__global__ void k_edge_feat(const float* __restrict__ z, const float* __restrict__ wm,
                            float* __restrict__ ef) {
    __shared__ float zg[NN*ZD];     // 1280 floats
    __shared__ float T[ZD*TSTR];    // 1056 floats
    int gph = blockIdx.x >> 1, par = blockIdx.x & 1;
    int t = threadIdx.x;
    for (int i = t; i < NN*ZD; i += 256) zg[i] = z[gph*NN*ZD + i];
    __syncthreads();
    for (int i = par; i < NN-1; i += 2) {
        // T[d][b] = sum_a zg[i][a] * wm[d,a,b]
#pragma unroll
        for (int q = 0; q < 4; ++q) {
            int idx = t + q*256;
            int d = idx >> 5, b = idx & 31;
            float acc = 0.f;
#pragma unroll
            for (int a = 0; a < ZD; ++a) acc += zg[i*ZD + a] * wm[d*1024 + a*32 + b];
            T[d*TSTR + b] = acc;
        }
        __syncthreads();
        int nj = NN - 1 - i;
        int base = gph*EPG + i*(2*NN-1-i)/2;      // global edge row of (i, i+1)
        for (int idx = t; idx < nj*ZD; idx += 256) {
            int jj = i + 1 + (idx >> 5);
            int d  = idx & 31;
            float acc = 0.f;
#pragma unroll
            for (int b = 0; b < ZD; ++b) acc += T[d*TSTR + b] * zg[jj*ZD + b];
            ef[(base + (jj - i - 1))*ZD + d] = acc;
        }
        __syncthreads();
    }
}

#define BROWS 64
__global__ void k_bond_stats(const float* __restrict__ ef, const float* __restrict__ bw1,
                             const float* __restrict__ bb1, float* __restrict__ stats) {
    __shared__ float efs[BROWS*ZD];   // 8 KB
    int r0 = blockIdx.x * BROWS;
    int t = threadIdx.x;
    for (int i = t; i < BROWS*ZD; i += HIDN) efs[i] = ef[r0*ZD + i];
    __syncthreads();
    float b = bb1[t], s = 0.f, ss = 0.f;
    for (int r = 0; r < BROWS; ++r) {
        float acc = b;
#pragma unroll
        for (int a = 0; a < ZD; ++a) acc += efs[r*ZD + a] * bw1[a*HIDN + t];
        s += acc; ss += acc*acc;
    }
    atomicAdd(&stats[2*HIDN + t], s);
    atomicAdd(&stats[3*HIDN + t], ss);
}

#define OROWS 8
__global__ void k_bond_out(const float* __restrict__ ef, const float* __restrict__ bw1,
                           const float* __restrict__ bb1, const float* __restrict__ stats,
                           const float* __restrict__ bg, const float* __restrict__ bbe,
                           const float* __restrict__ ba, const float* __restrict__ bw2,
                           const float* __restrict__ bb2, float* __restrict__ out) {
    __shared__ float efs[OROWS*ZD];     // 256
    __shared__ float p[OROWS*PSTR];
    __shared__ float o[OROWS*NBOND];
    int r0 = blockIdx.x * OROWS;
    int t = threadIdx.x;
    float aP = ba[0];
    const float invE = 1.0f / (float)NE;
    efs[t] = ef[r0*ZD + t];             // OROWS*ZD == 256 == blockDim
    __syncthreads();
    {
        int c = t;
        float m  = stats[2*HIDN + c] * invE;
        float v  = stats[3*HIDN + c] * invE - m*m;
        float rs = (1.0f/sqrtf(v + 1e-5f)) * bg[c];
        float be = bbe[c];
        float acc[OROWS];
#pragma unroll
        for (int r = 0; r < OROWS; ++r) acc[r] = bb1[c];
#pragma unroll
        for (int a = 0; a < ZD; ++a) {
            float w = bw1[a*HIDN + c];
#pragma unroll
            for (int r = 0; r < OROWS; ++r) acc[r] += efs[r*ZD + a] * w;
        }
#pragma unroll
        for (int r = 0; r < OROWS; ++r) {
            float xn = (acc[r] - m) * rs + be;
            p[r*PSTR + c] = xn >= 0.f ? xn : aP*xn;
        }
    }
    __syncthreads();
    if (t < OROWS*NBOND) {
        int r = t / NBOND, k = t % NBOND;
        float acc = bb2[k];
        for (int c = 0; c < HIDN; ++c) acc += p[r*PSTR + c] * bw2[c*NBOND + k];
        o[r*NBOND + k] = acc;
    }
    __syncthreads();
    if (t < OROWS) {
        float m = -INFINITY;
#pragma unroll
        for (int k = 0; k < NBOND; ++k) m = fmaxf(m, o[t*NBOND + k]);
        float e[NBOND]; float S = 0.f;
#pragma unroll
        for (int k = 0; k < NBOND; ++k) { e[k] = expf(o[t*NBOND + k] - m); S += e[k]; }
#pragma unroll
        for (int k = 0; k < NBOND; ++k) out[(r0+t)*NBOND + k] = e[k] / S;
    }
}

extern "C" void kernel_launch(void* const* d_in, const int* in_sizes, int n_in,
                              void* d_out, int out_size, void* d_ws, size_t ws_size,
                              hipStream_t stream) {
    (void)in_sizes; (void)n_in; (void)out_size; (void)ws_size;
    const float* eta  = (const float*)d_in[0];
    const float* gum  = (const float*)d_in[1];
    const float* noi  = (const float*)d_in[2];
    // d_in[3] edge_index, d_in[4] node_graph_idx: structure is deterministic, derived on device
    const float* cw1  = (const float*)d_in[5];
    const float* cb1  = (const float*)d_in[6];
    const float* cg   = (const float*)d_in[7];
    const float* cbe  = (const float*)d_in[8];
    const float* ca   = (const float*)d_in[9];
    const float* cw2  = (const float*)d_in[10];
    const float* cb2  = (const float*)d_in[11];
    const float* cm   = (const float*)d_in[12];
    const float* cls  = (const float*)d_in[13];
    const float* aw1  = (const float*)d_in[14];
    const float* ab1  = (const float*)d_in[15];
    const float* ag   = (const float*)d_in[16];
    const float* abe  = (const float*)d_in[17];
    const float* aa   = (const float*)d_in[18];
    const float* aw2  = (const float*)d_in[19];
    const float* ab2  = (const float*)d_in[20];
    const float* bm   = (const float*)d_in[21];
    const float* bw1  = (const float*)d_in[22];
    const float* bb1  = (const float*)d_in[23];
    const float* bg   = (const float*)d_in[24];
    const float* bbe  = (const float*)d_in[25];
    const float* ba   = (const float*)d_in[26];
    const float* bw2  = (const float*)d_in[27];
    const float* bb2  = (const float*)d_in[28];
    float* out = (float*)d_out;
    float* ws  = (float*)d_ws;

    // ws layout (floats)
    float* stats  = ws;             // 1024: atom_sum, atom_ssq, bond_sum, bond_ssq
    float* log_pi = ws + 1024;      // 4096
    float* cmean  = ws + 5120;      // 256
    float* cvar   = ws + 5376;      // 256
    float* h1     = ws + 5632;      // 32768
    float* zbuf   = ws + 38400;     // 163840
    float* h_atom = ws + 202240;    // 1310720
    float* wmb    = ws + 1512960;   // 32768
    float* efb    = ws + 1545728;   // 3194880  (total 4740608 floats ~ 18.1 MiB)

    hipMemsetAsync(stats, 0, 1024*sizeof(float), stream);
    k_class_h1   <<<dim3(BG),        dim3(HIDN), 0, stream>>>(eta, cw1, cb1, h1);
    k_class_stats<<<dim3(1),         dim3(HIDN), 0, stream>>>(h1, cmean, cvar);
    k_class_out  <<<dim3(BG),        dim3(HIDN), 0, stream>>>(h1, cmean, cvar, cg, cbe, ca, cw2, cb2, log_pi);
    k_node_z     <<<dim3(NA/256),    dim3(256),  0, stream>>>(log_pi, gum, noi, cm, cls, zbuf);
    k_atom_h     <<<dim3(NA/AROWS),  dim3(HIDN), 0, stream>>>(zbuf, aw1, ab1, h_atom, stats);
    k_atom_out   <<<dim3(NA/ORROWS), dim3(HIDN), 0, stream>>>(h_atom, stats, ag, abe, aa, aw2, ab2, out);
    k_wm         <<<dim3(128),       dim3(256),  0, stream>>>(bm, wmb);
    k_edge_feat  <<<dim3(2*BG),      dim3(256),  0, stream>>>(zbuf, wmb, efb);
    k_bond_stats <<<dim3(NE/BROWS),  dim3(HIDN), 0, stream>>>(efb, bw1, bb1, stats);
    k_bond_out   <<<dim3(NE/OROWS),  dim3(HIDN), 0, stream>>>(efb, bw1, bb1, stats, bg, bbe, ba, bw2, bb2, out + NA*NATOM);
}

// Round 2
// 253.672 us; speedup vs baseline: 1.4483x; 1.4483x over previous
//
#include <hip/hip_runtime.h>
#include <math.h>

#define BG    128                      // graphs (B)
#define NN    40                       // nodes per graph
#define AK    32                       // K (mixture comps)
#define ZD    32                       // Z latent dim
#define HIDN  256                      // HID
#define ETAD  64                       // ETA
#define NATOM 24
#define NBOND 5
#define NA    (BG*NN)                  // 5120 nodes
#define EPG   (NN*(NN-1)/2)            // 780 edges per graph
#define NE    (BG*EPG)                 // 99840 edges

// ---------------- class head ----------------
__global__ void k_class_h1(const float* __restrict__ eta, const float* __restrict__ cw1,
                           const float* __restrict__ cb1, float* __restrict__ h1) {
    __shared__ float es[ETAD];
    int r = blockIdx.x, c = threadIdx.x;
    if (c < ETAD) es[c] = eta[r*ETAD + c];
    __syncthreads();
    float acc = cb1[c];
#pragma unroll
    for (int a = 0; a < ETAD; ++a) acc += es[a] * cw1[a*HIDN + c];
    h1[r*HIDN + c] = acc;
}

__global__ void k_class_stats(const float* __restrict__ h1, float* __restrict__ mean,
                              float* __restrict__ var) {
    int c = threadIdx.x;
    float s = 0.f;
    for (int r = 0; r < BG; ++r) s += h1[r*HIDN + c];
    float m = s / (float)BG;
    float v = 0.f;
    for (int r = 0; r < BG; ++r) { float d = h1[r*HIDN + c] - m; v += d*d; }
    mean[c] = m;
    var[c]  = v / (float)BG;
}

__global__ void k_class_out(const float* __restrict__ h1, const float* __restrict__ mean,
                            const float* __restrict__ var, const float* __restrict__ cg,
                            const float* __restrict__ cbe, const float* __restrict__ ca,
                            const float* __restrict__ cw2, const float* __restrict__ cb2,
                            float* __restrict__ log_pi) {
    __shared__ float p[HIDN];
    __shared__ float o[AK];
    int r = blockIdx.x, t = threadIdx.x;
    float a = ca[0];
    {
        float x = h1[r*HIDN + t];
        float m = mean[t], v = var[t];
        float xn = (x - m) * (1.0f/sqrtf(v + 1e-5f)) * cg[t] + cbe[t];
        p[t] = xn >= 0.f ? xn : a*xn;
    }
    __syncthreads();
    if (t < AK) {
        float acc = cb2[t];
        for (int c = 0; c < HIDN; ++c) acc += p[c] * cw2[c*AK + t];
        o[t] = acc;
    }
    __syncthreads();
    if (t < AK) {
        float m = -INFINITY;
#pragma unroll
        for (int k = 0; k < AK; ++k) m = fmaxf(m, o[k]);
        float S = 0.f;
#pragma unroll
        for (int k = 0; k < AK; ++k) S += expf(o[k] - m);
        log_pi[r*AK + t] = o[t] - m - logf(S);
    }
}

// ---------------- gumbel + latent z ----------------
__global__ void k_node_z(const float* __restrict__ log_pi, const float* __restrict__ gum,
                         const float* __restrict__ noise, const float* __restrict__ cm,
                         const float* __restrict__ cls, float* __restrict__ z) {
    int n = blockIdx.x*blockDim.x + threadIdx.x;
    if (n >= NA) return;
    int g = n / NN;
    float x[AK];
    float m = -INFINITY;
#pragma unroll
    for (int k = 0; k < AK; ++k) {
        float u  = gum[n*AK + k];
        float gk = -logf(-logf(u));
        float xk = log_pi[g*AK + k] + gk;     // TAU == 1.0
        x[k] = xk; m = fmaxf(m, xk);
    }
    float S = 0.f;
#pragma unroll
    for (int k = 0; k < AK; ++k) { float e = expf(x[k] - m); x[k] = e; S += e; }
    float best = -INFINITY; int am = 0;
#pragma unroll
    for (int k = 0; k < AK; ++k) { float s = x[k] / S; if (s > best) { best = s; am = k; } }
    float cam = (1.0f - best) + best;          // exact fp replication of y_hard - sg(y) + y
#pragma unroll
    for (int j = 0; j < ZD; ++j) {
        float ls = cam * cls[am*ZD + j];
        ls = fminf(fmaxf(ls, -20.0f), 30.0f);
        z[n*ZD + j] = noise[n*ZD + j] * expf(ls) + cam * cm[am*ZD + j];
    }
}

// ---------------- atom MLP ----------------
#define AROWS 20
__global__ void k_atom_h(const float* __restrict__ z, const float* __restrict__ aw1,
                         const float* __restrict__ ab1, float* __restrict__ h,
                         float* __restrict__ stats) {
    __shared__ float zs[AROWS*ZD];
    int r0 = blockIdx.x * AROWS;
    int t = threadIdx.x;
    for (int i = t; i < AROWS*ZD; i += HIDN) zs[i] = z[r0*ZD + i];
    __syncthreads();
    float b = ab1[t], s = 0.f, ss = 0.f;
    for (int r = 0; r < AROWS; ++r) {
        float acc = b;
#pragma unroll
        for (int a = 0; a < ZD; ++a) acc += zs[r*ZD + a] * aw1[a*HIDN + t];
        h[(r0+r)*HIDN + t] = acc;
        s += acc; ss += acc*acc;
    }
    atomicAdd(&stats[t], s);
    atomicAdd(&stats[HIDN + t], ss);
}

#define ORROWS 8
#define PSTR   260    // padded LDS row stride (bank-conflict-free: stride%32==4)
__global__ void k_atom_out(const float* __restrict__ h, const float* __restrict__ stats,
                           const float* __restrict__ ag, const float* __restrict__ abe,
                           const float* __restrict__ aa, const float* __restrict__ aw2,
                           const float* __restrict__ ab2, float* __restrict__ out) {
    __shared__ float p[ORROWS*PSTR];
    int r0 = blockIdx.x * ORROWS;
    int t = threadIdx.x;
    float a = aa[0];
    const float invA = 1.0f / (float)NA;
    for (int idx = t; idx < ORROWS*HIDN; idx += HIDN) {
        int r = idx >> 8, c = idx & 255;
        float x = h[(r0+r)*HIDN + c];
        float m = stats[c] * invA;
        float v = stats[HIDN + c] * invA - m*m;
        float xn = (x - m) * (1.0f/sqrtf(v + 1e-5f)) * ag[c] + abe[c];
        p[r*PSTR + c] = xn >= 0.f ? xn : a*xn;
    }
    __syncthreads();
    if (t < ORROWS*NATOM) {
        int r = t / NATOM, k = t % NATOM;
        float acc = ab2[k];
        for (int c = 0; c < HIDN; ++c) acc += p[r*PSTR + c] * aw2[c*NATOM + k];
        out[(r0+r)*NATOM + k] = acc;
    }
}

// ---------------- edge featurizer v2 ----------------
// One block per (graph, d-group of 4). LDS: z (pad 36), Wm slice (symmetrized
// from bm on the fly), T tile (pad 36), pair table. Each thread owns whole
// edges in phase E (z_j row in registers, 4 d-outputs -> one float4 store).
#define DG   4
#define ZSTR 36
#define TSTR2 36
__global__ void k_edge_feat(const float* __restrict__ z, const float* __restrict__ bm,
                            float* __restrict__ ef) {
    __shared__ float zg[NN*ZSTR];        // 1440
    __shared__ float wmS[DG*ZD*ZD];      // 4096
    __shared__ float T[NN*DG*TSTR2];     // 5760
    __shared__ int   tbl[EPG];           // 780
    int g  = blockIdx.x >> 3;
    int dg = blockIdx.x & 7;
    int t  = threadIdx.x;

    // stage z (padded rows)
    for (int idx = t; idx < NN*ZD; idx += 256) {
        int i = idx >> 5, a = idx & 31;
        zg[i*ZSTR + a] = z[g*NN*ZD + idx];
    }
    // stage symmetrized Wm slice: wmS[dd][a][b] = 0.5*(bm[d][a][b]+bm[d][b][a])
#pragma unroll
    for (int k = 0; k < DG*ZD*ZD/256; ++k) {
        int idx = k*256 + t;
        int dd = idx >> 10, ab = idx & 1023, a = ab >> 5, b = ab & 31;
        int d = dg*DG + dd;
        wmS[idx] = 0.5f * (bm[d*1024 + a*32 + b] + bm[d*1024 + b*32 + a]);
    }
    // pair table
    for (int e = t; e < EPG; e += 256) {
        int i = 0, rem = e;
        while (rem >= NN - 1 - i) { rem -= NN - 1 - i; ++i; }
        tbl[e] = (i << 8) | (i + 1 + rem);
    }
    __syncthreads();

    // phase T: T[i][dd][b] = sum_a zg[i][a] * wmS[dd][a][b]
    {
        int b  = t & 31;
        int dd = (t >> 5) & 3;
        int i0 = t >> 7;
        float wreg[ZD];
#pragma unroll
        for (int a = 0; a < ZD; ++a) wreg[a] = wmS[dd*1024 + a*32 + b];
#pragma unroll
        for (int q = 0; q < NN/2; ++q) {
            int i = i0 + 2*q;
            float acc = 0.f;
#pragma unroll
            for (int a = 0; a < ZD; ++a) acc += zg[i*ZSTR + a] * wreg[a];
            T[(i*DG + dd)*TSTR2 + b] = acc;
        }
    }
    __syncthreads();

    // phase E: per edge, all 4 dd outputs
    size_t gE = (size_t)g * EPG;
    for (int e = t; e < EPG; e += 256) {
        int pk = tbl[e]; int i = pk >> 8, j = pk & 255;
        float4 zr[8];
#pragma unroll
        for (int q = 0; q < 8; ++q) zr[q] = *(const float4*)&zg[j*ZSTR + 4*q];
        float o[DG];
#pragma unroll
        for (int dd = 0; dd < DG; ++dd) {
            const float* Tr = &T[(i*DG + dd)*TSTR2];
            float acc = 0.f;
#pragma unroll
            for (int q = 0; q < 8; ++q) {
                float4 tq = *(const float4*)&Tr[4*q];
                acc += tq.x*zr[q].x + tq.y*zr[q].y + tq.z*zr[q].z + tq.w*zr[q].w;
            }
            o[dd] = acc;
        }
        *(float4*)&ef[(gE + e)*ZD + dg*DG] = make_float4(o[0], o[1], o[2], o[3]);
    }
}

// ---------------- bond MLP ----------------
#define BROWS 64
__global__ void k_bond_stats(const float* __restrict__ ef, const float* __restrict__ bw1,
                             const float* __restrict__ bb1, float* __restrict__ stats) {
    __shared__ float efs[BROWS*ZD];   // 8 KB
    int r0 = blockIdx.x * BROWS;
    int t = threadIdx.x;
    for (int i = t; i < BROWS*ZD; i += HIDN) efs[i] = ef[(size_t)r0*ZD + i];
    __syncthreads();
    float b = bb1[t], s = 0.f, ss = 0.f;
    for (int r = 0; r < BROWS; ++r) {
        float acc = b;
#pragma unroll
        for (int a = 0; a < ZD; ++a) acc += efs[r*ZD + a] * bw1[a*HIDN + t];
        s += acc; ss += acc*acc;
    }
    atomicAdd(&stats[2*HIDN + t], s);
    atomicAdd(&stats[3*HIDN + t], ss);
}

#define OROWS 8
__global__ void k_bond_out(const float* __restrict__ ef, const float* __restrict__ bw1,
                           const float* __restrict__ bb1, const float* __restrict__ stats,
                           const float* __restrict__ bg, const float* __restrict__ bbe,
                           const float* __restrict__ ba, const float* __restrict__ bw2,
                           const float* __restrict__ bb2, float* __restrict__ out) {
    __shared__ float efs[OROWS*ZD];     // 256
    __shared__ float p[OROWS*PSTR];
    __shared__ float o[OROWS*NBOND];
    int r0 = blockIdx.x * OROWS;
    int t = threadIdx.x;
    float aP = ba[0];
    const float invE = 1.0f / (float)NE;
    efs[t] = ef[(size_t)r0*ZD + t];     // OROWS*ZD == 256 == blockDim
    __syncthreads();
    {
        int c = t;
        float m  = stats[2*HIDN + c] * invE;
        float v  = stats[3*HIDN + c] * invE - m*m;
        float rs = (1.0f/sqrtf(v + 1e-5f)) * bg[c];
        float be = bbe[c];
        float acc[OROWS];
#pragma unroll
        for (int r = 0; r < OROWS; ++r) acc[r] = bb1[c];
#pragma unroll
        for (int a = 0; a < ZD; ++a) {
            float w = bw1[a*HIDN + c];
#pragma unroll
            for (int r = 0; r < OROWS; ++r) acc[r] += efs[r*ZD + a] * w;
        }
#pragma unroll
        for (int r = 0; r < OROWS; ++r) {
            float xn = (acc[r] - m) * rs + be;
            p[r*PSTR + c] = xn >= 0.f ? xn : aP*xn;
        }
    }
    __syncthreads();
    if (t < OROWS*NBOND) {
        int r = t / NBOND, k = t % NBOND;
        float acc = bb2[k];
        for (int c = 0; c < HIDN; ++c) acc += p[r*PSTR + c] * bw2[c*NBOND + k];
        o[r*NBOND + k] = acc;
    }
    __syncthreads();
    if (t < OROWS) {
        float m = -INFINITY;
#pragma unroll
        for (int k = 0; k < NBOND; ++k) m = fmaxf(m, o[t*NBOND + k]);
        float e[NBOND]; float S = 0.f;
#pragma unroll
        for (int k = 0; k < NBOND; ++k) { e[k] = expf(o[t*NBOND + k] - m); S += e[k]; }
#pragma unroll
        for (int k = 0; k < NBOND; ++k) out[(size_t)(r0+t)*NBOND + k] = e[k] / S;
    }
}

extern "C" void kernel_launch(void* const* d_in, const int* in_sizes, int n_in,
                              void* d_out, int out_size, void* d_ws, size_t ws_size,
                              hipStream_t stream) {
    (void)in_sizes; (void)n_in; (void)out_size; (void)ws_size;
    const float* eta  = (const float*)d_in[0];
    const float* gum  = (const float*)d_in[1];
    const float* noi  = (const float*)d_in[2];
    // d_in[3] edge_index, d_in[4] node_graph_idx: structure is deterministic, derived on device
    const float* cw1  = (const float*)d_in[5];
    const float* cb1  = (const float*)d_in[6];
    const float* cg   = (const float*)d_in[7];
    const float* cbe  = (const float*)d_in[8];
    const float* ca   = (const float*)d_in[9];
    const float* cw2  = (const float*)d_in[10];
    const float* cb2  = (const float*)d_in[11];
    const float* cm   = (const float*)d_in[12];
    const float* cls  = (const float*)d_in[13];
    const float* aw1  = (const float*)d_in[14];
    const float* ab1  = (const float*)d_in[15];
    const float* ag   = (const float*)d_in[16];
    const float* abe  = (const float*)d_in[17];
    const float* aa   = (const float*)d_in[18];
    const float* aw2  = (const float*)d_in[19];
    const float* ab2  = (const float*)d_in[20];
    const float* bm   = (const float*)d_in[21];
    const float* bw1  = (const float*)d_in[22];
    const float* bb1  = (const float*)d_in[23];
    const float* bg   = (const float*)d_in[24];
    const float* bbe  = (const float*)d_in[25];
    const float* ba   = (const float*)d_in[26];
    const float* bw2  = (const float*)d_in[27];
    const float* bb2  = (const float*)d_in[28];
    float* out = (float*)d_out;
    float* ws  = (float*)d_ws;

    // ws layout (floats)
    float* stats  = ws;             // 1024: atom_sum, atom_ssq, bond_sum, bond_ssq
    float* log_pi = ws + 1024;      // 4096
    float* cmean  = ws + 5120;      // 256
    float* cvar   = ws + 5376;      // 256
    float* h1     = ws + 5632;      // 32768
    float* zbuf   = ws + 38400;     // 163840
    float* h_atom = ws + 202240;    // 1310720
    float* efb    = ws + 1512960;   // 3194880  (total ~18.0 MiB)

    hipMemsetAsync(stats, 0, 1024*sizeof(float), stream);
    k_class_h1   <<<dim3(BG),        dim3(HIDN), 0, stream>>>(eta, cw1, cb1, h1);
    k_class_stats<<<dim3(1),         dim3(HIDN), 0, stream>>>(h1, cmean, cvar);
    k_class_out  <<<dim3(BG),        dim3(HIDN), 0, stream>>>(h1, cmean, cvar, cg, cbe, ca, cw2, cb2, log_pi);
    k_node_z     <<<dim3(NA/256),    dim3(256),  0, stream>>>(log_pi, gum, noi, cm, cls, zbuf);
    k_atom_h     <<<dim3(NA/AROWS),  dim3(HIDN), 0, stream>>>(zbuf, aw1, ab1, h_atom, stats);
    k_atom_out   <<<dim3(NA/ORROWS), dim3(HIDN), 0, stream>>>(h_atom, stats, ag, abe, aa, aw2, ab2, out);
    k_edge_feat  <<<dim3(8*BG),      dim3(256),  0, stream>>>(zbuf, bm, efb);
    k_bond_stats <<<dim3(NE/BROWS),  dim3(HIDN), 0, stream>>>(efb, bw1, bb1, stats);
    k_bond_out   <<<dim3(NE/OROWS),  dim3(HIDN), 0, stream>>>(efb, bw1, bb1, stats, bg, bbe, ba, bw2, bb2, out + NA*NATOM);
}

// Round 3
// 226.319 us; speedup vs baseline: 1.6233x; 1.1209x over previous
//
#include <hip/hip_runtime.h>
#include <math.h>

#define BG    128                      // graphs (B)
#define NN    40                       // nodes per graph
#define AK    32                       // K (mixture comps)
#define ZD    32                       // Z latent dim
#define HIDN  256                      // HID
#define ETAD  64                       // ETA
#define NATOM 24
#define NBOND 5
#define NA    (BG*NN)                  // 5120 nodes
#define EPG   (NN*(NN-1)/2)            // 780 edges per graph
#define NE    (BG*EPG)                 // 99840 edges
#define PP    257                      // padded LDS stride (2-way max on all patterns)

// ---------------- class head ----------------
__global__ void k_class_h1(const float* __restrict__ eta, const float* __restrict__ cw1,
                           const float* __restrict__ cb1, float* __restrict__ h1) {
    __shared__ float es[ETAD];
    int r = blockIdx.x, c = threadIdx.x;
    if (c < ETAD) es[c] = eta[r*ETAD + c];
    __syncthreads();
    float acc = cb1[c];
#pragma unroll
    for (int a = 0; a < ETAD; ++a) acc += es[a] * cw1[a*HIDN + c];
    h1[r*HIDN + c] = acc;
}

__global__ void k_class_stats(const float* __restrict__ h1, float* __restrict__ mean,
                              float* __restrict__ var) {
    int c = threadIdx.x;
    float s = 0.f;
    for (int r = 0; r < BG; ++r) s += h1[r*HIDN + c];
    float m = s / (float)BG;
    float v = 0.f;
    for (int r = 0; r < BG; ++r) { float d = h1[r*HIDN + c] - m; v += d*d; }
    mean[c] = m;
    var[c]  = v / (float)BG;
}

__global__ void k_class_out(const float* __restrict__ h1, const float* __restrict__ mean,
                            const float* __restrict__ var, const float* __restrict__ cg,
                            const float* __restrict__ cbe, const float* __restrict__ ca,
                            const float* __restrict__ cw2, const float* __restrict__ cb2,
                            float* __restrict__ log_pi) {
    __shared__ float p[HIDN];
    __shared__ float o[AK];
    int r = blockIdx.x, t = threadIdx.x;
    float a = ca[0];
    {
        float x = h1[r*HIDN + t];
        float m = mean[t], v = var[t];
        float xn = (x - m) * (1.0f/sqrtf(v + 1e-5f)) * cg[t] + cbe[t];
        p[t] = xn >= 0.f ? xn : a*xn;
    }
    __syncthreads();
    if (t < AK) {
        float acc = cb2[t];
        for (int c = 0; c < HIDN; ++c) acc += p[c] * cw2[c*AK + t];
        o[t] = acc;
    }
    __syncthreads();
    if (t < AK) {
        float m = -INFINITY;
#pragma unroll
        for (int k = 0; k < AK; ++k) m = fmaxf(m, o[k]);
        float S = 0.f;
#pragma unroll
        for (int k = 0; k < AK; ++k) S += expf(o[k] - m);
        log_pi[r*AK + t] = o[t] - m - logf(S);
    }
}

// ---------------- gumbel + latent z ----------------
__global__ void k_node_z(const float* __restrict__ log_pi, const float* __restrict__ gum,
                         const float* __restrict__ noise, const float* __restrict__ cm,
                         const float* __restrict__ cls, float* __restrict__ z) {
    int n = blockIdx.x*blockDim.x + threadIdx.x;
    if (n >= NA) return;
    int g = n / NN;
    float x[AK];
    float m = -INFINITY;
#pragma unroll
    for (int k = 0; k < AK; ++k) {
        float u  = gum[n*AK + k];
        float gk = -logf(-logf(u));
        float xk = log_pi[g*AK + k] + gk;     // TAU == 1.0
        x[k] = xk; m = fmaxf(m, xk);
    }
    float S = 0.f;
#pragma unroll
    for (int k = 0; k < AK; ++k) { float e = expf(x[k] - m); x[k] = e; S += e; }
    float best = -INFINITY; int am = 0;
#pragma unroll
    for (int k = 0; k < AK; ++k) { float s = x[k] / S; if (s > best) { best = s; am = k; } }
    float cam = (1.0f - best) + best;          // exact fp replication of y_hard - sg(y) + y
#pragma unroll
    for (int j = 0; j < ZD; ++j) {
        float ls = cam * cls[am*ZD + j];
        ls = fminf(fmaxf(ls, -20.0f), 30.0f);
        z[n*ZD + j] = noise[n*ZD + j] * expf(ls) + cam * cm[am*ZD + j];
    }
}

// ---------------- row moments: mean(32) + second-moment M(32x32) ----------------
// 256 rows per block. mom layout: [0,1024) = sum x_a x_b ; [1024,1056) = sum x_a
__global__ __launch_bounds__(256) void k_moment(const float* __restrict__ src,
                                                float* __restrict__ mom) {
    __shared__ float s[256*36];
    int t = threadIdx.x;
    size_t base = (size_t)blockIdx.x * (256*ZD);
#pragma unroll
    for (int q = 0; q < 8; ++q) {
        int i4 = q*256 + t;
        int r = i4 >> 3, a4 = (i4 & 7) << 2;
        *(float4*)&s[r*36 + a4] = *(const float4*)&src[base + r*ZD + a4];
    }
    __syncthreads();
    int a = t >> 3, b4 = (t & 7) << 2;
    float ax = 0.f, ay = 0.f, az = 0.f, aw = 0.f;
    float mx = 0.f, my = 0.f, mz = 0.f, mw = 0.f;
    for (int r = 0; r < 256; ++r) {
        float  va = s[r*36 + a];
        float4 vb = *(const float4*)&s[r*36 + b4];
        ax += va*vb.x; ay += va*vb.y; az += va*vb.z; aw += va*vb.w;
        mx += vb.x;    my += vb.y;    mz += vb.z;    mw += vb.w;
    }
    atomicAdd(&mom[a*ZD + b4 + 0], ax);
    atomicAdd(&mom[a*ZD + b4 + 1], ay);
    atomicAdd(&mom[a*ZD + b4 + 2], az);
    atomicAdd(&mom[a*ZD + b4 + 3], aw);
    if (a == 0) {
        atomicAdd(&mom[ZD*ZD + b4 + 0], mx);
        atomicAdd(&mom[ZD*ZD + b4 + 1], my);
        atomicAdd(&mom[ZD*ZD + b4 + 2], mz);
        atomicAdd(&mom[ZD*ZD + b4 + 3], mw);
    }
}

// ---------------- BN params from moments: var_c = w_c^T Cov w_c ----------------
// grid 8 blocks x 256; block handles 32 channels; 8 partial a-groups each.
__global__ __launch_bounds__(256) void k_prep(const float* __restrict__ mom,
                                              const float* __restrict__ w1,
                                              const float* __restrict__ b1,
                                              const float* __restrict__ g,
                                              const float* __restrict__ be,
                                              float inv_n,
                                              float* __restrict__ scale,
                                              float* __restrict__ shift) {
    __shared__ float mean[ZD];
    __shared__ float cov[ZD*ZD];
    __shared__ float vp[256], mp[256];
    int t = threadIdx.x;
    if (t < ZD) mean[t] = mom[ZD*ZD + t] * inv_n;
    __syncthreads();
    for (int pp = t; pp < ZD*ZD; pp += 256) {
        int a = pp >> 5, b = pp & 31;
        cov[pp] = mom[pp] * inv_n - mean[a]*mean[b];
    }
    __syncthreads();
    int c = blockIdx.x * 32 + (t & 31);
    int part = t >> 5;
    float wr[ZD];
#pragma unroll
    for (int b = 0; b < ZD; ++b) wr[b] = w1[b*HIDN + c];
    float var = 0.f, mh = 0.f;
#pragma unroll
    for (int q = 0; q < 4; ++q) {
        int a = part*4 + q;
        float tmp = 0.f;
#pragma unroll
        for (int b = 0; b < ZD; ++b) tmp += cov[a*ZD + b] * wr[b];
        var += tmp * wr[a];
        mh  += mean[a] * wr[a];
    }
    vp[t] = var; mp[t] = mh;
    __syncthreads();
    if (t < 32) {
        float v = 0.f, m = 0.f;
#pragma unroll
        for (int q = 0; q < 8; ++q) { v += vp[q*32 + t]; m += mp[q*32 + t]; }
        m += b1[c];
        float rs = rsqrtf(fmaxf(v, 0.f) + 1e-5f) * g[c];
        scale[c] = rs;
        shift[c] = be[c] - m * rs;
    }
}

// ---------------- fused atom MLP (stats precomputed) ----------------
#define AOR 8
__global__ __launch_bounds__(256) void k_atom_f(const float* __restrict__ z,
                                                const float* __restrict__ aw1,
                                                const float* __restrict__ ab1,
                                                const float* __restrict__ ascale,
                                                const float* __restrict__ ashift,
                                                const float* __restrict__ aa,
                                                const float* __restrict__ aw2,
                                                const float* __restrict__ ab2,
                                                float* __restrict__ out) {
    __shared__ float p[AOR*PP];
    __shared__ float aws[HIDN*NATOM];   // 24 KB
    int t = threadIdx.x;
    size_t r0 = (size_t)blockIdx.x * AOR;
    for (int i = t; i < HIDN*NATOM; i += 256) aws[i] = aw2[i];
    // phase 1: h = z @ aw1 (z reads are wave-uniform -> scalar loads)
    int c = t;
    float wreg[ZD];
#pragma unroll
    for (int a = 0; a < ZD; ++a) wreg[a] = aw1[a*HIDN + c];
    float sc = ascale[c];
    float shc = ashift[c] + ab1[c]*sc;
    float aP = aa[0];
    const float* zb = &z[r0*ZD];
#pragma unroll
    for (int r = 0; r < AOR; ++r) {
        float s = 0.f;
#pragma unroll
        for (int a = 0; a < ZD; ++a) s += zb[r*ZD + a] * wreg[a];
        float xn = s*sc + shc;
        p[r*PP + c] = xn >= 0.f ? xn : aP*xn;
    }
    __syncthreads();
    // phase 2: out = prelu @ aw2   (192 threads: (r,k))
    if (t < AOR*NATOM) {
        int r = t / NATOM, k = t % NATOM;
        float acc = ab2[k];
#pragma unroll 8
        for (int cc = 0; cc < HIDN; ++cc) acc += p[r*PP + cc] * aws[cc*NATOM + k];
        out[(r0 + r)*NATOM + k] = acc;
    }
}

// ---------------- edge featurizer ----------------
#define DG   4
#define ZSTR 36
#define TSTR2 36
__global__ void k_edge_feat(const float* __restrict__ z, const float* __restrict__ bm,
                            float* __restrict__ ef) {
    __shared__ float zg[NN*ZSTR];        // 1440
    __shared__ float wmS[DG*ZD*ZD];      // 4096
    __shared__ float T[NN*DG*TSTR2];     // 5760
    __shared__ int   tbl[EPG];           // 780
    int g  = blockIdx.x >> 3;
    int dg = blockIdx.x & 7;
    int t  = threadIdx.x;

    for (int idx = t; idx < NN*ZD; idx += 256) {
        int i = idx >> 5, a = idx & 31;
        zg[i*ZSTR + a] = z[g*NN*ZD + idx];
    }
#pragma unroll
    for (int k = 0; k < DG*ZD*ZD/256; ++k) {
        int idx = k*256 + t;
        int dd = idx >> 10, ab = idx & 1023, a = ab >> 5, b = ab & 31;
        int d = dg*DG + dd;
        wmS[idx] = 0.5f * (bm[d*1024 + a*32 + b] + bm[d*1024 + b*32 + a]);
    }
    for (int e = t; e < EPG; e += 256) {
        int i = 0, rem = e;
        while (rem >= NN - 1 - i) { rem -= NN - 1 - i; ++i; }
        tbl[e] = (i << 8) | (i + 1 + rem);
    }
    __syncthreads();

    // phase T: T[i][dd][b] = sum_a zg[i][a] * wmS[dd][a][b]
    {
        int b  = t & 31;
        int dd = (t >> 5) & 3;
        int i0 = t >> 7;
        float wreg[ZD];
#pragma unroll
        for (int a = 0; a < ZD; ++a) wreg[a] = wmS[dd*1024 + a*32 + b];
#pragma unroll
        for (int q = 0; q < NN/2; ++q) {
            int i = i0 + 2*q;
            float acc = 0.f;
#pragma unroll
            for (int a = 0; a < ZD; ++a) acc += zg[i*ZSTR + a] * wreg[a];
            T[(i*DG + dd)*TSTR2 + b] = acc;
        }
    }
    __syncthreads();

    // phase E
    size_t gE = (size_t)g * EPG;
    for (int e = t; e < EPG; e += 256) {
        int pk = tbl[e]; int i = pk >> 8, j = pk & 255;
        float4 zr[8];
#pragma unroll
        for (int q = 0; q < 8; ++q) zr[q] = *(const float4*)&zg[j*ZSTR + 4*q];
        float o[DG];
#pragma unroll
        for (int dd = 0; dd < DG; ++dd) {
            const float* Tr = &T[(i*DG + dd)*TSTR2];
            float acc = 0.f;
#pragma unroll
            for (int q = 0; q < 8; ++q) {
                float4 tq = *(const float4*)&Tr[4*q];
                acc += tq.x*zr[q].x + tq.y*zr[q].y + tq.z*zr[q].z + tq.w*zr[q].w;
            }
            o[dd] = acc;
        }
        *(float4*)&ef[(gE + e)*ZD + dg*DG] = make_float4(o[0], o[1], o[2], o[3]);
    }
}

// ---------------- bond MLP single pass (stats precomputed) ----------------
#define BOR 32
__global__ __launch_bounds__(256) void k_bond_out(const float* __restrict__ ef,
                                                  const float* __restrict__ bw1,
                                                  const float* __restrict__ bb1,
                                                  const float* __restrict__ bscale,
                                                  const float* __restrict__ bshift,
                                                  const float* __restrict__ ba,
                                                  const float* __restrict__ bw2,
                                                  const float* __restrict__ bb2,
                                                  float* __restrict__ out) {
    __shared__ float p[BOR*PP];          // 32.9 KB
    __shared__ float bws[HIDN*NBOND];    // 1280
    __shared__ float red[8*BOR*NBOND];   // 1280
    __shared__ float osm[BOR*NBOND];     // 160
    int t = threadIdx.x;
    size_t r0 = (size_t)blockIdx.x * BOR;
    for (int i = t; i < HIDN*NBOND; i += 256) bws[i] = bw2[i];
    // phase 1: h row-block (ef reads wave-uniform -> scalar loads; w in VGPRs)
    int c = t;
    float wreg[ZD];
#pragma unroll
    for (int a = 0; a < ZD; ++a) wreg[a] = bw1[a*HIDN + c];
    float sc = bscale[c];
    float shc = bshift[c] + bb1[c]*sc;
    float aP = ba[0];
    const float* efb = &ef[r0*ZD];
#pragma unroll
    for (int r = 0; r < BOR; ++r) {
        float s = 0.f;
#pragma unroll
        for (int a = 0; a < ZD; ++a) s += efb[r*ZD + a] * wreg[a];
        float xn = s*sc + shc;
        p[r*PP + c] = xn >= 0.f ? xn : aP*xn;
    }
    __syncthreads();
    // phase 2: (r,cc) chunked second layer
    {
        int rr = t & 31, cc = t >> 5;
        float a5[NBOND] = {0.f,0.f,0.f,0.f,0.f};
        const float* pr = &p[rr*PP + cc*32];
        const float* wr = &bws[cc*32*NBOND];
#pragma unroll
        for (int j = 0; j < 32; ++j) {
            float pv = pr[j];
#pragma unroll
            for (int k = 0; k < NBOND; ++k) a5[k] += pv * wr[j*NBOND + k];
        }
#pragma unroll
        for (int k = 0; k < NBOND; ++k) red[(cc*BOR + rr)*NBOND + k] = a5[k];
    }
    __syncthreads();
    if (t < BOR*NBOND) {
        float s = bb2[t % NBOND];
#pragma unroll
        for (int q = 0; q < 8; ++q) s += red[q*BOR*NBOND + t];
        osm[t] = s;
    }
    __syncthreads();
    if (t < BOR) {
        float m = -INFINITY;
#pragma unroll
        for (int k = 0; k < NBOND; ++k) m = fmaxf(m, osm[t*NBOND + k]);
        float e[NBOND]; float S = 0.f;
#pragma unroll
        for (int k = 0; k < NBOND; ++k) { e[k] = expf(osm[t*NBOND + k] - m); S += e[k]; }
        float invS = 1.f / S;
#pragma unroll
        for (int k = 0; k < NBOND; ++k) out[(r0 + t)*NBOND + k] = e[k] * invS;
    }
}

extern "C" void kernel_launch(void* const* d_in, const int* in_sizes, int n_in,
                              void* d_out, int out_size, void* d_ws, size_t ws_size,
                              hipStream_t stream) {
    (void)in_sizes; (void)n_in; (void)out_size; (void)ws_size;
    const float* eta  = (const float*)d_in[0];
    const float* gum  = (const float*)d_in[1];
    const float* noi  = (const float*)d_in[2];
    const float* cw1  = (const float*)d_in[5];
    const float* cb1  = (const float*)d_in[6];
    const float* cg   = (const float*)d_in[7];
    const float* cbe  = (const float*)d_in[8];
    const float* ca   = (const float*)d_in[9];
    const float* cw2  = (const float*)d_in[10];
    const float* cb2  = (const float*)d_in[11];
    const float* cm   = (const float*)d_in[12];
    const float* cls  = (const float*)d_in[13];
    const float* aw1  = (const float*)d_in[14];
    const float* ab1  = (const float*)d_in[15];
    const float* ag   = (const float*)d_in[16];
    const float* abe  = (const float*)d_in[17];
    const float* aa   = (const float*)d_in[18];
    const float* aw2  = (const float*)d_in[19];
    const float* ab2  = (const float*)d_in[20];
    const float* bm   = (const float*)d_in[21];
    const float* bw1  = (const float*)d_in[22];
    const float* bb1  = (const float*)d_in[23];
    const float* bg   = (const float*)d_in[24];
    const float* bbe  = (const float*)d_in[25];
    const float* ba   = (const float*)d_in[26];
    const float* bw2  = (const float*)d_in[27];
    const float* bb2  = (const float*)d_in[28];
    float* out = (float*)d_out;
    float* ws  = (float*)d_ws;

    // ws layout (floats)
    float* mom_z  = ws;             // 1056
    float* mom_ef = ws + 1056;      // 1056
    float* ascale = ws + 2112;      // 256
    float* ashift = ws + 2368;      // 256
    float* bscale = ws + 2624;      // 256
    float* bshift = ws + 2880;      // 256
    float* log_pi = ws + 3136;      // 4096
    float* cmean  = ws + 7232;      // 256
    float* cvar   = ws + 7488;      // 256
    float* h1     = ws + 7744;      // 32768
    float* zbuf   = ws + 40512;     // 163840
    float* efb    = ws + 204352;    // 3194880   (total ~13.0 MiB)

    hipMemsetAsync(ws, 0, 2112*sizeof(float), stream);
    k_class_h1   <<<dim3(BG),       dim3(HIDN), 0, stream>>>(eta, cw1, cb1, h1);
    k_class_stats<<<dim3(1),        dim3(HIDN), 0, stream>>>(h1, cmean, cvar);
    k_class_out  <<<dim3(BG),       dim3(HIDN), 0, stream>>>(h1, cmean, cvar, cg, cbe, ca, cw2, cb2, log_pi);
    k_node_z     <<<dim3(NA/256),   dim3(256),  0, stream>>>(log_pi, gum, noi, cm, cls, zbuf);
    k_moment     <<<dim3(NA/256),   dim3(256),  0, stream>>>(zbuf, mom_z);
    k_prep       <<<dim3(8),        dim3(256),  0, stream>>>(mom_z, aw1, ab1, ag, abe, 1.0f/(float)NA, ascale, ashift);
    k_atom_f     <<<dim3(NA/AOR),   dim3(256),  0, stream>>>(zbuf, aw1, ab1, ascale, ashift, aa, aw2, ab2, out);
    k_edge_feat  <<<dim3(8*BG),     dim3(256),  0, stream>>>(zbuf, bm, efb);
    k_moment     <<<dim3(NE/256),   dim3(256),  0, stream>>>(efb, mom_ef);
    k_prep       <<<dim3(8),        dim3(256),  0, stream>>>(mom_ef, bw1, bb1, bg, bbe, 1.0f/(float)NE, bscale, bshift);
    k_bond_out   <<<dim3(NE/BOR),   dim3(256),  0, stream>>>(efb, bw1, bb1, bscale, bshift, ba, bw2, bb2, out + NA*NATOM);
}

// Round 4
// 165.035 us; speedup vs baseline: 2.2262x; 1.3713x over previous
//
#include <hip/hip_runtime.h>
#include <math.h>

#define BG    128                      // graphs (B)
#define NN    40                       // nodes per graph
#define AK    32                       // K (mixture comps)
#define ZD    32                       // Z latent dim
#define HIDN  256                      // HID
#define ETAD  64                       // ETA
#define NATOM 24
#define NBOND 5
#define NA    (BG*NN)                  // 5120 nodes
#define EPG   (NN*(NN-1)/2)            // 780 edges per graph
#define NE    (BG*EPG)                 // 99840 edges
#define PP    257                      // padded LDS stride

typedef __attribute__((ext_vector_type(8))) short bf16x8;
typedef __attribute__((ext_vector_type(4))) float f32x4;

__device__ __forceinline__ unsigned short f2bf(float f) {
    union { float f; unsigned int u; } x; x.f = f;
    unsigned int r = x.u + 0x7fffu + ((x.u >> 16) & 1u);   // RNE
    return (unsigned short)(r >> 16);
}

// ---------------- class head ----------------
__global__ void k_class_h1(const float* __restrict__ eta, const float* __restrict__ cw1,
                           const float* __restrict__ cb1, float* __restrict__ h1) {
    __shared__ float es[ETAD];
    int r = blockIdx.x, c = threadIdx.x;
    if (c < ETAD) es[c] = eta[r*ETAD + c];
    __syncthreads();
    float acc = cb1[c];
#pragma unroll
    for (int a = 0; a < ETAD; ++a) acc += es[a] * cw1[a*HIDN + c];
    h1[r*HIDN + c] = acc;
}

__global__ void k_class_stats(const float* __restrict__ h1, float* __restrict__ mean,
                              float* __restrict__ var) {
    int c = threadIdx.x;
    float s = 0.f;
    for (int r = 0; r < BG; ++r) s += h1[r*HIDN + c];
    float m = s / (float)BG;
    float v = 0.f;
    for (int r = 0; r < BG; ++r) { float d = h1[r*HIDN + c] - m; v += d*d; }
    mean[c] = m;
    var[c]  = v / (float)BG;
}

__global__ void k_class_out(const float* __restrict__ h1, const float* __restrict__ mean,
                            const float* __restrict__ var, const float* __restrict__ cg,
                            const float* __restrict__ cbe, const float* __restrict__ ca,
                            const float* __restrict__ cw2, const float* __restrict__ cb2,
                            float* __restrict__ log_pi) {
    __shared__ float p[HIDN];
    __shared__ float o[AK];
    int r = blockIdx.x, t = threadIdx.x;
    float a = ca[0];
    {
        float x = h1[r*HIDN + t];
        float m = mean[t], v = var[t];
        float xn = (x - m) * (1.0f/sqrtf(v + 1e-5f)) * cg[t] + cbe[t];
        p[t] = xn >= 0.f ? xn : a*xn;
    }
    __syncthreads();
    if (t < AK) {
        float acc = cb2[t];
        for (int c = 0; c < HIDN; ++c) acc += p[c] * cw2[c*AK + t];
        o[t] = acc;
    }
    __syncthreads();
    if (t < AK) {
        float m = -INFINITY;
#pragma unroll
        for (int k = 0; k < AK; ++k) m = fmaxf(m, o[k]);
        float S = 0.f;
#pragma unroll
        for (int k = 0; k < AK; ++k) S += expf(o[k] - m);
        log_pi[r*AK + t] = o[t] - m - logf(S);
    }
}

// ---------------- gumbel + latent z ----------------
__global__ void k_node_z(const float* __restrict__ log_pi, const float* __restrict__ gum,
                         const float* __restrict__ noise, const float* __restrict__ cm,
                         const float* __restrict__ cls, float* __restrict__ z) {
    int n = blockIdx.x*blockDim.x + threadIdx.x;
    if (n >= NA) return;
    int g = n / NN;
    float x[AK];
    float m = -INFINITY;
#pragma unroll
    for (int k = 0; k < AK; ++k) {
        float u  = gum[n*AK + k];
        float gk = -logf(-logf(u));
        float xk = log_pi[g*AK + k] + gk;     // TAU == 1.0
        x[k] = xk; m = fmaxf(m, xk);
    }
    float S = 0.f;
#pragma unroll
    for (int k = 0; k < AK; ++k) { float e = expf(x[k] - m); x[k] = e; S += e; }
    float best = -INFINITY; int am = 0;
#pragma unroll
    for (int k = 0; k < AK; ++k) { float s = x[k] / S; if (s > best) { best = s; am = k; } }
    float cam = (1.0f - best) + best;          // exact fp replication of y_hard - sg(y) + y
#pragma unroll
    for (int j = 0; j < ZD; ++j) {
        float ls = cam * cls[am*ZD + j];
        ls = fminf(fmaxf(ls, -20.0f), 30.0f);
        z[n*ZD + j] = noise[n*ZD + j] * expf(ls) + cam * cm[am*ZD + j];
    }
}

// ---------------- row moments: mean(32) + second-moment M(32x32) ----------------
__global__ __launch_bounds__(256) void k_moment(const float* __restrict__ src,
                                                float* __restrict__ mom) {
    __shared__ float s[256*36];
    int t = threadIdx.x;
    size_t base = (size_t)blockIdx.x * (256*ZD);
#pragma unroll
    for (int q = 0; q < 8; ++q) {
        int i4 = q*256 + t;
        int r = i4 >> 3, a4 = (i4 & 7) << 2;
        *(float4*)&s[r*36 + a4] = *(const float4*)&src[base + r*ZD + a4];
    }
    __syncthreads();
    int a = t >> 3, b4 = (t & 7) << 2;
    float ax = 0.f, ay = 0.f, az = 0.f, aw = 0.f;
    float mx = 0.f, my = 0.f, mz = 0.f, mw = 0.f;
    for (int r = 0; r < 256; ++r) {
        float  va = s[r*36 + a];
        float4 vb = *(const float4*)&s[r*36 + b4];
        ax += va*vb.x; ay += va*vb.y; az += va*vb.z; aw += va*vb.w;
        mx += vb.x;    my += vb.y;    mz += vb.z;    mw += vb.w;
    }
    atomicAdd(&mom[a*ZD + b4 + 0], ax);
    atomicAdd(&mom[a*ZD + b4 + 1], ay);
    atomicAdd(&mom[a*ZD + b4 + 2], az);
    atomicAdd(&mom[a*ZD + b4 + 3], aw);
    if (a == 0) {
        atomicAdd(&mom[ZD*ZD + b4 + 0], mx);
        atomicAdd(&mom[ZD*ZD + b4 + 1], my);
        atomicAdd(&mom[ZD*ZD + b4 + 2], mz);
        atomicAdd(&mom[ZD*ZD + b4 + 3], mw);
    }
}

// ---------------- BN params from moments ----------------
__global__ __launch_bounds__(256) void k_prep(const float* __restrict__ mom,
                                              const float* __restrict__ w1,
                                              const float* __restrict__ b1,
                                              const float* __restrict__ g,
                                              const float* __restrict__ be,
                                              float inv_n,
                                              float* __restrict__ scale,
                                              float* __restrict__ shift) {
    __shared__ float mean[ZD];
    __shared__ float cov[ZD*ZD];
    __shared__ float vp[256], mp[256];
    int t = threadIdx.x;
    if (t < ZD) mean[t] = mom[ZD*ZD + t] * inv_n;
    __syncthreads();
    for (int pp = t; pp < ZD*ZD; pp += 256) {
        int a = pp >> 5, b = pp & 31;
        cov[pp] = mom[pp] * inv_n - mean[a]*mean[b];
    }
    __syncthreads();
    int c = blockIdx.x * 32 + (t & 31);
    int part = t >> 5;
    float wr[ZD];
#pragma unroll
    for (int b = 0; b < ZD; ++b) wr[b] = w1[b*HIDN + c];
    float var = 0.f, mh = 0.f;
#pragma unroll
    for (int q = 0; q < 4; ++q) {
        int a = part*4 + q;
        float tmp = 0.f;
#pragma unroll
        for (int b = 0; b < ZD; ++b) tmp += cov[a*ZD + b] * wr[b];
        var += tmp * wr[a];
        mh  += mean[a] * wr[a];
    }
    vp[t] = var; mp[t] = mh;
    __syncthreads();
    if (t < 32) {
        float v = 0.f, m = 0.f;
#pragma unroll
        for (int q = 0; q < 8; ++q) { v += vp[q*32 + t]; m += mp[q*32 + t]; }
        m += b1[c];
        float rs = rsqrtf(fmaxf(v, 0.f) + 1e-5f) * g[c];
        scale[c] = rs;
        shift[c] = be[c] - m * rs;
    }
}

// ---------------- fused atom MLP ----------------
#define AOR 8
__global__ __launch_bounds__(256) void k_atom_f(const float* __restrict__ z,
                                                const float* __restrict__ aw1,
                                                const float* __restrict__ ab1,
                                                const float* __restrict__ ascale,
                                                const float* __restrict__ ashift,
                                                const float* __restrict__ aa,
                                                const float* __restrict__ aw2,
                                                const float* __restrict__ ab2,
                                                float* __restrict__ out) {
    __shared__ float p[AOR*PP];
    __shared__ float aws[HIDN*NATOM];   // 24 KB
    int t = threadIdx.x;
    size_t r0 = (size_t)blockIdx.x * AOR;
    for (int i = t; i < HIDN*NATOM; i += 256) aws[i] = aw2[i];
    int c = t;
    float wreg[ZD];
#pragma unroll
    for (int a = 0; a < ZD; ++a) wreg[a] = aw1[a*HIDN + c];
    float sc = ascale[c];
    float shc = ashift[c] + ab1[c]*sc;
    float aP = aa[0];
    const float* zb = &z[r0*ZD];
#pragma unroll
    for (int r = 0; r < AOR; ++r) {
        float s = 0.f;
#pragma unroll
        for (int a = 0; a < ZD; ++a) s += zb[r*ZD + a] * wreg[a];
        float xn = s*sc + shc;
        p[r*PP + c] = xn >= 0.f ? xn : aP*xn;
    }
    __syncthreads();
    if (t < AOR*NATOM) {
        int r = t / NATOM, k = t % NATOM;
        float acc = ab2[k];
#pragma unroll 8
        for (int cc = 0; cc < HIDN; ++cc) acc += p[r*PP + cc] * aws[cc*NATOM + k];
        out[(r0 + r)*NATOM + k] = acc;
    }
}

// ---------------- edge featurizer ----------------
#define DG   4
#define ZSTR 36
#define TSTR2 36
__global__ void k_edge_feat(const float* __restrict__ z, const float* __restrict__ bm,
                            float* __restrict__ ef) {
    __shared__ float zg[NN*ZSTR];        // 1440
    __shared__ float wmS[DG*ZD*ZD];      // 4096
    __shared__ float T[NN*DG*TSTR2];     // 5760
    __shared__ int   tbl[EPG];           // 780
    int g  = blockIdx.x >> 3;
    int dg = blockIdx.x & 7;
    int t  = threadIdx.x;

    for (int idx = t; idx < NN*ZD; idx += 256) {
        int i = idx >> 5, a = idx & 31;
        zg[i*ZSTR + a] = z[g*NN*ZD + idx];
    }
#pragma unroll
    for (int k = 0; k < DG*ZD*ZD/256; ++k) {
        int idx = k*256 + t;
        int dd = idx >> 10, ab = idx & 1023, a = ab >> 5, b = ab & 31;
        int d = dg*DG + dd;
        wmS[idx] = 0.5f * (bm[d*1024 + a*32 + b] + bm[d*1024 + b*32 + a]);
    }
    for (int e = t; e < EPG; e += 256) {
        int i = 0, rem = e;
        while (rem >= NN - 1 - i) { rem -= NN - 1 - i; ++i; }
        tbl[e] = (i << 8) | (i + 1 + rem);
    }
    __syncthreads();

    {
        int b  = t & 31;
        int dd = (t >> 5) & 3;
        int i0 = t >> 7;
        float wreg[ZD];
#pragma unroll
        for (int a = 0; a < ZD; ++a) wreg[a] = wmS[dd*1024 + a*32 + b];
#pragma unroll
        for (int q = 0; q < NN/2; ++q) {
            int i = i0 + 2*q;
            float acc = 0.f;
#pragma unroll
            for (int a = 0; a < ZD; ++a) acc += zg[i*ZSTR + a] * wreg[a];
            T[(i*DG + dd)*TSTR2 + b] = acc;
        }
    }
    __syncthreads();

    size_t gE = (size_t)g * EPG;
    for (int e = t; e < EPG; e += 256) {
        int pk = tbl[e]; int i = pk >> 8, j = pk & 255;
        float4 zr[8];
#pragma unroll
        for (int q = 0; q < 8; ++q) zr[q] = *(const float4*)&zg[j*ZSTR + 4*q];
        float o[DG];
#pragma unroll
        for (int dd = 0; dd < DG; ++dd) {
            const float* Tr = &T[(i*DG + dd)*TSTR2];
            float acc = 0.f;
#pragma unroll
            for (int q = 0; q < 8; ++q) {
                float4 tq = *(const float4*)&Tr[4*q];
                acc += tq.x*zr[q].x + tq.y*zr[q].y + tq.z*zr[q].z + tq.w*zr[q].w;
            }
            o[dd] = acc;
        }
        *(float4*)&ef[(gE + e)*ZD + dg*DG] = make_float4(o[0], o[1], o[2], o[3]);
    }
}

// ---------------- pack bw1 into per-lane-contiguous bf16 B-fragments ----------------
// bpack[ct*512 + lane*8 + j] = bf16( bw1[ (8*(lane>>4)+j)*HIDN + ct*16 + (lane&15) ] )
__global__ __launch_bounds__(256) void k_wpack(const float* __restrict__ bw1,
                                               unsigned short* __restrict__ bp) {
    int idx = blockIdx.x*256 + threadIdx.x;          // 8192 total
    int ct = idx >> 9, rem = idx & 511;
    int lane = rem >> 3, j = rem & 7;
    float v = bw1[((lane >> 4)*8 + j)*HIDN + ct*16 + (lane & 15)];
    bp[idx] = f2bf(v);
}

// ---------------- bond MLP: MFMA phase-1 + in-register phase-2 ----------------
#define BROWS4 64
__global__ __launch_bounds__(256) void k_bond_out(const float* __restrict__ ef,
                                                  const unsigned short* __restrict__ bpack,
                                                  const float* __restrict__ bb1,
                                                  const float* __restrict__ bscale,
                                                  const float* __restrict__ bshift,
                                                  const float* __restrict__ ba,
                                                  const float* __restrict__ bw2,
                                                  const float* __restrict__ bb2,
                                                  float* __restrict__ out) {
    __shared__ float w2s[HIDN*NBOND];    // 1280
    __shared__ float scs[HIDN];
    __shared__ float shs[HIDN];
    int t = threadIdx.x;
    size_t r0 = (size_t)blockIdx.x * BROWS4;

    for (int i = t; i < HIDN*NBOND; i += 256) w2s[i] = bw2[i];
    { float sc = bscale[t]; scs[t] = sc; shs[t] = bshift[t] + bb1[t]*sc; }
    __syncthreads();

    int lane = t & 63, w = t >> 6;
    int l15 = lane & 15, gq = lane >> 4;
    float aP = ba[0];
    float b2r[NBOND];
#pragma unroll
    for (int k = 0; k < NBOND; ++k) b2r[k] = bb2[k];

    // A fragment: row = r0 + 16*w + l15, k = 8*gq + j  (fp32 load -> bf16)
    const float* ar = &ef[(r0 + (size_t)w*16 + l15)*ZD + gq*8];
    float4 a0 = *(const float4*)ar;
    float4 a1 = *(const float4*)(ar + 4);
    bf16x8 af;
    af[0] = (short)f2bf(a0.x); af[1] = (short)f2bf(a0.y);
    af[2] = (short)f2bf(a0.z); af[3] = (short)f2bf(a0.w);
    af[4] = (short)f2bf(a1.x); af[5] = (short)f2bf(a1.y);
    af[6] = (short)f2bf(a1.z); af[7] = (short)f2bf(a1.w);

    float part[4][NBOND];
#pragma unroll
    for (int r = 0; r < 4; ++r)
#pragma unroll
        for (int k = 0; k < NBOND; ++k) part[r][k] = 0.f;

    f32x4 zero4 = {0.f, 0.f, 0.f, 0.f};
#pragma unroll
    for (int h = 0; h < 2; ++h) {
        bf16x8 bf[8];
#pragma unroll
        for (int q = 0; q < 8; ++q)
            bf[q] = *(const bf16x8*)&bpack[(h*8 + q)*512 + lane*8];
        f32x4 acc[8];
#pragma unroll
        for (int q = 0; q < 8; ++q)
            acc[q] = __builtin_amdgcn_mfma_f32_16x16x32_bf16(af, bf[q], zero4, 0, 0, 0);
        // BN + PReLU + second layer accumulate.  C layout: col=l15, row=4*gq+reg
#pragma unroll
        for (int q = 0; q < 8; ++q) {
            int c = (h*8 + q)*16 + l15;
            float sc = scs[c], sh = shs[c];
            float w0 = w2s[c*NBOND+0], w1v = w2s[c*NBOND+1], w2v = w2s[c*NBOND+2];
            float w3 = w2s[c*NBOND+3], w4 = w2s[c*NBOND+4];
#pragma unroll
            for (int r = 0; r < 4; ++r) {
                float xn = acc[q][r]*sc + sh;
                float pv = xn >= 0.f ? xn : aP*xn;
                part[r][0] += pv*w0; part[r][1] += pv*w1v; part[r][2] += pv*w2v;
                part[r][3] += pv*w3; part[r][4] += pv*w4;
            }
        }
    }

    // reduce over the 16 lanes (l15) of each gq group
#pragma unroll
    for (int s = 1; s < 16; s <<= 1) {
#pragma unroll
        for (int r = 0; r < 4; ++r)
#pragma unroll
            for (int k = 0; k < NBOND; ++k)
                part[r][k] += __shfl_xor(part[r][k], s, 64);
    }

    if (l15 == 0) {
#pragma unroll
        for (int r = 0; r < 4; ++r) {
            size_t row = r0 + (size_t)w*16 + gq*4 + r;
            float lg[NBOND];
            float m = -INFINITY;
#pragma unroll
            for (int k = 0; k < NBOND; ++k) { lg[k] = part[r][k] + b2r[k]; m = fmaxf(m, lg[k]); }
            float S = 0.f;
#pragma unroll
            for (int k = 0; k < NBOND; ++k) { lg[k] = expf(lg[k] - m); S += lg[k]; }
            float invS = 1.f / S;
#pragma unroll
            for (int k = 0; k < NBOND; ++k) out[row*NBOND + k] = lg[k] * invS;
        }
    }
}

extern "C" void kernel_launch(void* const* d_in, const int* in_sizes, int n_in,
                              void* d_out, int out_size, void* d_ws, size_t ws_size,
                              hipStream_t stream) {
    (void)in_sizes; (void)n_in; (void)out_size; (void)ws_size;
    const float* eta  = (const float*)d_in[0];
    const float* gum  = (const float*)d_in[1];
    const float* noi  = (const float*)d_in[2];
    const float* cw1  = (const float*)d_in[5];
    const float* cb1  = (const float*)d_in[6];
    const float* cg   = (const float*)d_in[7];
    const float* cbe  = (const float*)d_in[8];
    const float* ca   = (const float*)d_in[9];
    const float* cw2  = (const float*)d_in[10];
    const float* cb2  = (const float*)d_in[11];
    const float* cm   = (const float*)d_in[12];
    const float* cls  = (const float*)d_in[13];
    const float* aw1  = (const float*)d_in[14];
    const float* ab1  = (const float*)d_in[15];
    const float* ag   = (const float*)d_in[16];
    const float* abe  = (const float*)d_in[17];
    const float* aa   = (const float*)d_in[18];
    const float* aw2  = (const float*)d_in[19];
    const float* ab2  = (const float*)d_in[20];
    const float* bm   = (const float*)d_in[21];
    const float* bw1  = (const float*)d_in[22];
    const float* bb1  = (const float*)d_in[23];
    const float* bg   = (const float*)d_in[24];
    const float* bbe  = (const float*)d_in[25];
    const float* ba   = (const float*)d_in[26];
    const float* bw2  = (const float*)d_in[27];
    const float* bb2  = (const float*)d_in[28];
    float* out = (float*)d_out;
    float* ws  = (float*)d_ws;

    // ws layout (floats)
    float*          mom_z  = ws;             // 1056
    float*          mom_ef = ws + 1056;      // 1056
    float*          ascale = ws + 2112;      // 256
    float*          ashift = ws + 2368;      // 256
    float*          bscale = ws + 2624;      // 256
    float*          bshift = ws + 2880;      // 256
    unsigned short* bpack  = (unsigned short*)(ws + 3136);  // 8192 ushort = 4096 floats
    float*          log_pi = ws + 7232;      // 4096
    float*          cmean  = ws + 11328;     // 256
    float*          cvar   = ws + 11584;     // 256
    float*          h1     = ws + 11840;     // 32768
    float*          zbuf   = ws + 44608;     // 163840
    float*          efb    = ws + 208448;    // 3194880   (total ~13.0 MiB)

    hipMemsetAsync(ws, 0, 2112*sizeof(float), stream);
    k_wpack      <<<dim3(32),       dim3(256),  0, stream>>>(bw1, bpack);
    k_class_h1   <<<dim3(BG),       dim3(HIDN), 0, stream>>>(eta, cw1, cb1, h1);
    k_class_stats<<<dim3(1),        dim3(HIDN), 0, stream>>>(h1, cmean, cvar);
    k_class_out  <<<dim3(BG),       dim3(HIDN), 0, stream>>>(h1, cmean, cvar, cg, cbe, ca, cw2, cb2, log_pi);
    k_node_z     <<<dim3(NA/256),   dim3(256),  0, stream>>>(log_pi, gum, noi, cm, cls, zbuf);
    k_moment     <<<dim3(NA/256),   dim3(256),  0, stream>>>(zbuf, mom_z);
    k_prep       <<<dim3(8),        dim3(256),  0, stream>>>(mom_z, aw1, ab1, ag, abe, 1.0f/(float)NA, ascale, ashift);
    k_atom_f     <<<dim3(NA/AOR),   dim3(256),  0, stream>>>(zbuf, aw1, ab1, ascale, ashift, aa, aw2, ab2, out);
    k_edge_feat  <<<dim3(8*BG),     dim3(256),  0, stream>>>(zbuf, bm, efb);
    k_moment     <<<dim3(NE/256),   dim3(256),  0, stream>>>(efb, mom_ef);
    k_prep       <<<dim3(8),        dim3(256),  0, stream>>>(mom_ef, bw1, bb1, bg, bbe, 1.0f/(float)NE, bscale, bshift);
    k_bond_out   <<<dim3(NE/BROWS4),dim3(256),  0, stream>>>(efb, bpack, bb1, bscale, bshift, ba, bw2, bb2, out + NA*NATOM);
}

// Round 5
// 135.265 us; speedup vs baseline: 2.7161x; 1.2201x over previous
//
#include <hip/hip_runtime.h>
#include <math.h>

#define BG    128                      // graphs (B)
#define NN    40                       // nodes per graph
#define AK    32                       // K (mixture comps)
#define ZD    32                       // Z latent dim
#define HIDN  256                      // HID
#define ETAD  64                       // ETA
#define NATOM 24
#define NBOND 5
#define NA    (BG*NN)                  // 5120 nodes
#define EPG   (NN*(NN-1)/2)            // 780 edges per graph
#define NE    (BG*EPG)                 // 99840 edges
#define PP    257                      // padded LDS stride

typedef __attribute__((ext_vector_type(8))) short bf16x8;
typedef __attribute__((ext_vector_type(4))) float f32x4;

__device__ __forceinline__ unsigned short f2bf(float f) {
    union { float f; unsigned int u; } x; x.f = f;
    unsigned int r = x.u + 0x7fffu + ((x.u >> 16) & 1u);   // RNE
    return (unsigned short)(r >> 16);
}

// ---------------- class head ----------------
__global__ void k_class_h1(const float* __restrict__ eta, const float* __restrict__ cw1,
                           const float* __restrict__ cb1, float* __restrict__ h1) {
    __shared__ float es[ETAD];
    int r = blockIdx.x, c = threadIdx.x;
    if (c < ETAD) es[c] = eta[r*ETAD + c];
    __syncthreads();
    float acc = cb1[c];
#pragma unroll
    for (int a = 0; a < ETAD; ++a) acc += es[a] * cw1[a*HIDN + c];
    h1[r*HIDN + c] = acc;
}

__global__ void k_class_stats(const float* __restrict__ h1, float* __restrict__ mean,
                              float* __restrict__ var) {
    int c = threadIdx.x;
    float s = 0.f;
    for (int r = 0; r < BG; ++r) s += h1[r*HIDN + c];
    float m = s / (float)BG;
    float v = 0.f;
    for (int r = 0; r < BG; ++r) { float d = h1[r*HIDN + c] - m; v += d*d; }
    mean[c] = m;
    var[c]  = v / (float)BG;
}

__global__ void k_class_out(const float* __restrict__ h1, const float* __restrict__ mean,
                            const float* __restrict__ var, const float* __restrict__ cg,
                            const float* __restrict__ cbe, const float* __restrict__ ca,
                            const float* __restrict__ cw2, const float* __restrict__ cb2,
                            float* __restrict__ log_pi) {
    __shared__ float p[HIDN];
    __shared__ float o[AK];
    int r = blockIdx.x, t = threadIdx.x;
    float a = ca[0];
    {
        float x = h1[r*HIDN + t];
        float m = mean[t], v = var[t];
        float xn = (x - m) * (1.0f/sqrtf(v + 1e-5f)) * cg[t] + cbe[t];
        p[t] = xn >= 0.f ? xn : a*xn;
    }
    __syncthreads();
    if (t < AK) {
        float acc = cb2[t];
        for (int c = 0; c < HIDN; ++c) acc += p[c] * cw2[c*AK + t];
        o[t] = acc;
    }
    __syncthreads();
    if (t < AK) {
        float m = -INFINITY;
#pragma unroll
        for (int k = 0; k < AK; ++k) m = fmaxf(m, o[k]);
        float S = 0.f;
#pragma unroll
        for (int k = 0; k < AK; ++k) S += expf(o[k] - m);
        log_pi[r*AK + t] = o[t] - m - logf(S);
    }
}

// ---------------- gumbel + latent z ----------------
__global__ void k_node_z(const float* __restrict__ log_pi, const float* __restrict__ gum,
                         const float* __restrict__ noise, const float* __restrict__ cm,
                         const float* __restrict__ cls, float* __restrict__ z) {
    int n = blockIdx.x*blockDim.x + threadIdx.x;
    if (n >= NA) return;
    int g = n / NN;
    float x[AK];
    float m = -INFINITY;
#pragma unroll
    for (int k = 0; k < AK; ++k) {
        float u  = gum[n*AK + k];
        float gk = -logf(-logf(u));
        float xk = log_pi[g*AK + k] + gk;     // TAU == 1.0
        x[k] = xk; m = fmaxf(m, xk);
    }
    float S = 0.f;
#pragma unroll
    for (int k = 0; k < AK; ++k) { float e = expf(x[k] - m); x[k] = e; S += e; }
    float best = -INFINITY; int am = 0;
#pragma unroll
    for (int k = 0; k < AK; ++k) { float s = x[k] / S; if (s > best) { best = s; am = k; } }
    float cam = (1.0f - best) + best;          // exact fp replication of y_hard - sg(y) + y
#pragma unroll
    for (int j = 0; j < ZD; ++j) {
        float ls = cam * cls[am*ZD + j];
        ls = fminf(fmaxf(ls, -20.0f), 30.0f);
        z[n*ZD + j] = noise[n*ZD + j] * expf(ls) + cam * cm[am*ZD + j];
    }
}

// ---------------- row moments via MFMA: mom[a*32+b] += sum x_a x_b ; mom[1024+a] += sum x_a
// One wave per 32-row chunk (grid-stride). A/B/C layouts = the session-validated
// 16x16x32 bf16 conventions. Mean accumulated in fp32 BEFORE bf16 conversion.
__global__ __launch_bounds__(256) void k_moment(const float* __restrict__ src,
                                                float* __restrict__ mom, int nchunks) {
    __shared__ float sm[ZD*ZD + ZD];   // 1056 floats
    int t = threadIdx.x;
    for (int i = t; i < ZD*ZD + ZD; i += 256) sm[i] = 0.f;
    __syncthreads();
    int lane = t & 63, wv = t >> 6;
    int l15 = lane & 15, g4 = lane >> 4;
    int wgid = blockIdx.x * 4 + wv;
    int nw = gridDim.x * 4;
    f32x4 aII = {0,0,0,0}, aIJ = {0,0,0,0}, aJI = {0,0,0,0}, aJJ = {0,0,0,0};
    float mI = 0.f, mJ = 0.f;
    for (int ch = wgid; ch < nchunks; ch += nw) {
        const float* p = src + ((size_t)ch*32 + g4*8)*ZD + l15;
        float vI[8], vJ[8];
#pragma unroll
        for (int j = 0; j < 8; ++j) { vI[j] = p[j*ZD]; vJ[j] = p[j*ZD + 16]; }
        bf16x8 fI, fJ;
#pragma unroll
        for (int j = 0; j < 8; ++j) {
            fI[j] = (short)f2bf(vI[j]); fJ[j] = (short)f2bf(vJ[j]);
            mI += vI[j]; mJ += vJ[j];
        }
        aII = __builtin_amdgcn_mfma_f32_16x16x32_bf16(fI, fI, aII, 0, 0, 0);
        aIJ = __builtin_amdgcn_mfma_f32_16x16x32_bf16(fI, fJ, aIJ, 0, 0, 0);
        aJI = __builtin_amdgcn_mfma_f32_16x16x32_bf16(fJ, fI, aJI, 0, 0, 0);
        aJJ = __builtin_amdgcn_mfma_f32_16x16x32_bf16(fJ, fJ, aJJ, 0, 0, 0);
    }
    // C layout: col = l15, row = g4*4 + r
#pragma unroll
    for (int r = 0; r < 4; ++r) {
        int row = g4*4 + r;
        atomicAdd(&sm[row*ZD + l15],           aII[r]);
        atomicAdd(&sm[row*ZD + 16 + l15],      aIJ[r]);
        atomicAdd(&sm[(16 + row)*ZD + l15],    aJI[r]);
        atomicAdd(&sm[(16 + row)*ZD + 16 + l15], aJJ[r]);
    }
    atomicAdd(&sm[ZD*ZD + l15], mI);
    atomicAdd(&sm[ZD*ZD + 16 + l15], mJ);
    __syncthreads();
    for (int i = t; i < ZD*ZD + ZD; i += 256) atomicAdd(&mom[i], sm[i]);
}

// ---------------- BN params from moments ----------------
__global__ __launch_bounds__(256) void k_prep(const float* __restrict__ mom,
                                              const float* __restrict__ w1,
                                              const float* __restrict__ b1,
                                              const float* __restrict__ g,
                                              const float* __restrict__ be,
                                              float inv_n,
                                              float* __restrict__ scale,
                                              float* __restrict__ shift) {
    __shared__ float mean[ZD];
    __shared__ float cov[ZD*ZD];
    __shared__ float vp[256], mp[256];
    int t = threadIdx.x;
    if (t < ZD) mean[t] = mom[ZD*ZD + t] * inv_n;
    __syncthreads();
    for (int pp = t; pp < ZD*ZD; pp += 256) {
        int a = pp >> 5, b = pp & 31;
        cov[pp] = mom[pp] * inv_n - mean[a]*mean[b];
    }
    __syncthreads();
    int c = blockIdx.x * 32 + (t & 31);
    int part = t >> 5;
    float wr[ZD];
#pragma unroll
    for (int b = 0; b < ZD; ++b) wr[b] = w1[b*HIDN + c];
    float var = 0.f, mh = 0.f;
#pragma unroll
    for (int q = 0; q < 4; ++q) {
        int a = part*4 + q;
        float tmp = 0.f;
#pragma unroll
        for (int b = 0; b < ZD; ++b) tmp += cov[a*ZD + b] * wr[b];
        var += tmp * wr[a];
        mh  += mean[a] * wr[a];
    }
    vp[t] = var; mp[t] = mh;
    __syncthreads();
    if (t < 32) {
        float v = 0.f, m = 0.f;
#pragma unroll
        for (int q = 0; q < 8; ++q) { v += vp[q*32 + t]; m += mp[q*32 + t]; }
        m += b1[c];
        float rs = rsqrtf(fmaxf(v, 0.f) + 1e-5f) * g[c];
        scale[c] = rs;
        shift[c] = be[c] - m * rs;
    }
}

// ---------------- fused atom MLP ----------------
#define AOR 8
__global__ __launch_bounds__(256) void k_atom_f(const float* __restrict__ z,
                                                const float* __restrict__ aw1,
                                                const float* __restrict__ ab1,
                                                const float* __restrict__ ascale,
                                                const float* __restrict__ ashift,
                                                const float* __restrict__ aa,
                                                const float* __restrict__ aw2,
                                                const float* __restrict__ ab2,
                                                float* __restrict__ out) {
    __shared__ float p[AOR*PP];
    __shared__ float aws[HIDN*NATOM];   // 24 KB
    int t = threadIdx.x;
    size_t r0 = (size_t)blockIdx.x * AOR;
    for (int i = t; i < HIDN*NATOM; i += 256) aws[i] = aw2[i];
    int c = t;
    float wreg[ZD];
#pragma unroll
    for (int a = 0; a < ZD; ++a) wreg[a] = aw1[a*HIDN + c];
    float sc = ascale[c];
    float shc = ashift[c] + ab1[c]*sc;
    float aP = aa[0];
    const float* zb = &z[r0*ZD];
#pragma unroll
    for (int r = 0; r < AOR; ++r) {
        float s = 0.f;
#pragma unroll
        for (int a = 0; a < ZD; ++a) s += zb[r*ZD + a] * wreg[a];
        float xn = s*sc + shc;
        p[r*PP + c] = xn >= 0.f ? xn : aP*xn;
    }
    __syncthreads();
    if (t < AOR*NATOM) {
        int r = t / NATOM, k = t % NATOM;
        float acc = ab2[k];
#pragma unroll 8
        for (int cc = 0; cc < HIDN; ++cc) acc += p[r*PP + cc] * aws[cc*NATOM + k];
        out[(r0 + r)*NATOM + k] = acc;
    }
}

// ---------------- edge featurizer ----------------
#define DG   4
#define ZSTR 36
#define TSTR2 36
__global__ void k_edge_feat(const float* __restrict__ z, const float* __restrict__ bm,
                            float* __restrict__ ef) {
    __shared__ float zg[NN*ZSTR];        // 1440
    __shared__ float wmS[DG*ZD*ZD];      // 4096
    __shared__ float T[NN*DG*TSTR2];     // 5760
    __shared__ int   tbl[EPG];           // 780
    int g  = blockIdx.x >> 3;
    int dg = blockIdx.x & 7;
    int t  = threadIdx.x;

    for (int idx = t; idx < NN*ZD; idx += 256) {
        int i = idx >> 5, a = idx & 31;
        zg[i*ZSTR + a] = z[g*NN*ZD + idx];
    }
#pragma unroll
    for (int k = 0; k < DG*ZD*ZD/256; ++k) {
        int idx = k*256 + t;
        int dd = idx >> 10, ab = idx & 1023, a = ab >> 5, b = ab & 31;
        int d = dg*DG + dd;
        wmS[idx] = 0.5f * (bm[d*1024 + a*32 + b] + bm[d*1024 + b*32 + a]);
    }
    for (int e = t; e < EPG; e += 256) {
        int i = 0, rem = e;
        while (rem >= NN - 1 - i) { rem -= NN - 1 - i; ++i; }
        tbl[e] = (i << 8) | (i + 1 + rem);
    }
    __syncthreads();

    {
        int b  = t & 31;
        int dd = (t >> 5) & 3;
        int i0 = t >> 7;
        float wreg[ZD];
#pragma unroll
        for (int a = 0; a < ZD; ++a) wreg[a] = wmS[dd*1024 + a*32 + b];
#pragma unroll
        for (int q = 0; q < NN/2; ++q) {
            int i = i0 + 2*q;
            float acc = 0.f;
#pragma unroll
            for (int a = 0; a < ZD; ++a) acc += zg[i*ZSTR + a] * wreg[a];
            T[(i*DG + dd)*TSTR2 + b] = acc;
        }
    }
    __syncthreads();

    size_t gE = (size_t)g * EPG;
    for (int e = t; e < EPG; e += 256) {
        int pk = tbl[e]; int i = pk >> 8, j = pk & 255;
        float4 zr[8];
#pragma unroll
        for (int q = 0; q < 8; ++q) zr[q] = *(const float4*)&zg[j*ZSTR + 4*q];
        float o[DG];
#pragma unroll
        for (int dd = 0; dd < DG; ++dd) {
            const float* Tr = &T[(i*DG + dd)*TSTR2];
            float acc = 0.f;
#pragma unroll
            for (int q = 0; q < 8; ++q) {
                float4 tq = *(const float4*)&Tr[4*q];
                acc += tq.x*zr[q].x + tq.y*zr[q].y + tq.z*zr[q].z + tq.w*zr[q].w;
            }
            o[dd] = acc;
        }
        *(float4*)&ef[(gE + e)*ZD + dg*DG] = make_float4(o[0], o[1], o[2], o[3]);
    }
}

// ---------------- pack bw1 into per-lane-contiguous bf16 B-fragments ----------------
__global__ __launch_bounds__(256) void k_wpack(const float* __restrict__ bw1,
                                               unsigned short* __restrict__ bp) {
    int idx = blockIdx.x*256 + threadIdx.x;          // 8192 total
    int ct = idx >> 9, rem = idx & 511;
    int lane = rem >> 3, j = rem & 7;
    float v = bw1[((lane >> 4)*8 + j)*HIDN + ct*16 + (lane & 15)];
    bp[idx] = f2bf(v);
}

// ---------------- bond MLP: MFMA phase-1 + in-register phase-2 ----------------
#define BROWS4 64
__global__ __launch_bounds__(256) void k_bond_out(const float* __restrict__ ef,
                                                  const unsigned short* __restrict__ bpack,
                                                  const float* __restrict__ bb1,
                                                  const float* __restrict__ bscale,
                                                  const float* __restrict__ bshift,
                                                  const float* __restrict__ ba,
                                                  const float* __restrict__ bw2,
                                                  const float* __restrict__ bb2,
                                                  float* __restrict__ out) {
    __shared__ float w2s[HIDN*NBOND];    // 1280
    __shared__ float scs[HIDN];
    __shared__ float shs[HIDN];
    int t = threadIdx.x;
    size_t r0 = (size_t)blockIdx.x * BROWS4;

    for (int i = t; i < HIDN*NBOND; i += 256) w2s[i] = bw2[i];
    { float sc = bscale[t]; scs[t] = sc; shs[t] = bshift[t] + bb1[t]*sc; }
    __syncthreads();

    int lane = t & 63, w = t >> 6;
    int l15 = lane & 15, gq = lane >> 4;
    float aP = ba[0];
    float b2r[NBOND];
#pragma unroll
    for (int k = 0; k < NBOND; ++k) b2r[k] = bb2[k];

    const float* ar = &ef[(r0 + (size_t)w*16 + l15)*ZD + gq*8];
    float4 a0 = *(const float4*)ar;
    float4 a1 = *(const float4*)(ar + 4);
    bf16x8 af;
    af[0] = (short)f2bf(a0.x); af[1] = (short)f2bf(a0.y);
    af[2] = (short)f2bf(a0.z); af[3] = (short)f2bf(a0.w);
    af[4] = (short)f2bf(a1.x); af[5] = (short)f2bf(a1.y);
    af[6] = (short)f2bf(a1.z); af[7] = (short)f2bf(a1.w);

    float part[4][NBOND];
#pragma unroll
    for (int r = 0; r < 4; ++r)
#pragma unroll
        for (int k = 0; k < NBOND; ++k) part[r][k] = 0.f;

    f32x4 zero4 = {0.f, 0.f, 0.f, 0.f};
#pragma unroll
    for (int h = 0; h < 2; ++h) {
        bf16x8 bf[8];
#pragma unroll
        for (int q = 0; q < 8; ++q)
            bf[q] = *(const bf16x8*)&bpack[(h*8 + q)*512 + lane*8];
        f32x4 acc[8];
#pragma unroll
        for (int q = 0; q < 8; ++q)
            acc[q] = __builtin_amdgcn_mfma_f32_16x16x32_bf16(af, bf[q], zero4, 0, 0, 0);
#pragma unroll
        for (int q = 0; q < 8; ++q) {
            int c = (h*8 + q)*16 + l15;
            float sc = scs[c], sh = shs[c];
            float w0 = w2s[c*NBOND+0], w1v = w2s[c*NBOND+1], w2v = w2s[c*NBOND+2];
            float w3 = w2s[c*NBOND+3], w4 = w2s[c*NBOND+4];
#pragma unroll
            for (int r = 0; r < 4; ++r) {
                float xn = acc[q][r]*sc + sh;
                float pv = xn >= 0.f ? xn : aP*xn;
                part[r][0] += pv*w0; part[r][1] += pv*w1v; part[r][2] += pv*w2v;
                part[r][3] += pv*w3; part[r][4] += pv*w4;
            }
        }
    }

#pragma unroll
    for (int s = 1; s < 16; s <<= 1) {
#pragma unroll
        for (int r = 0; r < 4; ++r)
#pragma unroll
            for (int k = 0; k < NBOND; ++k)
                part[r][k] += __shfl_xor(part[r][k], s, 64);
    }

    if (l15 == 0) {
#pragma unroll
        for (int r = 0; r < 4; ++r) {
            size_t row = r0 + (size_t)w*16 + gq*4 + r;
            float lg[NBOND];
            float m = -INFINITY;
#pragma unroll
            for (int k = 0; k < NBOND; ++k) { lg[k] = part[r][k] + b2r[k]; m = fmaxf(m, lg[k]); }
            float S = 0.f;
#pragma unroll
            for (int k = 0; k < NBOND; ++k) { lg[k] = expf(lg[k] - m); S += lg[k]; }
            float invS = 1.f / S;
#pragma unroll
            for (int k = 0; k < NBOND; ++k) out[row*NBOND + k] = lg[k] * invS;
        }
    }
}

extern "C" void kernel_launch(void* const* d_in, const int* in_sizes, int n_in,
                              void* d_out, int out_size, void* d_ws, size_t ws_size,
                              hipStream_t stream) {
    (void)in_sizes; (void)n_in; (void)out_size; (void)ws_size;
    const float* eta  = (const float*)d_in[0];
    const float* gum  = (const float*)d_in[1];
    const float* noi  = (const float*)d_in[2];
    const float* cw1  = (const float*)d_in[5];
    const float* cb1  = (const float*)d_in[6];
    const float* cg   = (const float*)d_in[7];
    const float* cbe  = (const float*)d_in[8];
    const float* ca   = (const float*)d_in[9];
    const float* cw2  = (const float*)d_in[10];
    const float* cb2  = (const float*)d_in[11];
    const float* cm   = (const float*)d_in[12];
    const float* cls  = (const float*)d_in[13];
    const float* aw1  = (const float*)d_in[14];
    const float* ab1  = (const float*)d_in[15];
    const float* ag   = (const float*)d_in[16];
    const float* abe  = (const float*)d_in[17];
    const float* aa   = (const float*)d_in[18];
    const float* aw2  = (const float*)d_in[19];
    const float* ab2  = (const float*)d_in[20];
    const float* bm   = (const float*)d_in[21];
    const float* bw1  = (const float*)d_in[22];
    const float* bb1  = (const float*)d_in[23];
    const float* bg   = (const float*)d_in[24];
    const float* bbe  = (const float*)d_in[25];
    const float* ba   = (const float*)d_in[26];
    const float* bw2  = (const float*)d_in[27];
    const float* bb2  = (const float*)d_in[28];
    float* out = (float*)d_out;
    float* ws  = (float*)d_ws;

    // ws layout (floats)
    float*          mom_z  = ws;             // 1056
    float*          mom_ef = ws + 1056;      // 1056
    float*          ascale = ws + 2112;      // 256
    float*          ashift = ws + 2368;      // 256
    float*          bscale = ws + 2624;      // 256
    float*          bshift = ws + 2880;      // 256
    unsigned short* bpack  = (unsigned short*)(ws + 3136);  // 8192 ushort = 4096 floats
    float*          log_pi = ws + 7232;      // 4096
    float*          cmean  = ws + 11328;     // 256
    float*          cvar   = ws + 11584;     // 256
    float*          h1     = ws + 11840;     // 32768
    float*          zbuf   = ws + 44608;     // 163840
    float*          efb    = ws + 208448;    // 3194880   (total ~13.0 MiB)

    hipMemsetAsync(ws, 0, 2112*sizeof(float), stream);
    k_wpack      <<<dim3(32),       dim3(256),  0, stream>>>(bw1, bpack);
    k_class_h1   <<<dim3(BG),       dim3(HIDN), 0, stream>>>(eta, cw1, cb1, h1);
    k_class_stats<<<dim3(1),        dim3(HIDN), 0, stream>>>(h1, cmean, cvar);
    k_class_out  <<<dim3(BG),       dim3(HIDN), 0, stream>>>(h1, cmean, cvar, cg, cbe, ca, cw2, cb2, log_pi);
    k_node_z     <<<dim3(NA/256),   dim3(256),  0, stream>>>(log_pi, gum, noi, cm, cls, zbuf);
    k_moment     <<<dim3(40),       dim3(256),  0, stream>>>(zbuf, mom_z, NA/32);
    k_prep       <<<dim3(8),        dim3(256),  0, stream>>>(mom_z, aw1, ab1, ag, abe, 1.0f/(float)NA, ascale, ashift);
    k_atom_f     <<<dim3(NA/AOR),   dim3(256),  0, stream>>>(zbuf, aw1, ab1, ascale, ashift, aa, aw2, ab2, out);
    k_edge_feat  <<<dim3(8*BG),     dim3(256),  0, stream>>>(zbuf, bm, efb);
    k_moment     <<<dim3(195),      dim3(256),  0, stream>>>(efb, mom_ef, NE/32);
    k_prep       <<<dim3(8),        dim3(256),  0, stream>>>(mom_ef, bw1, bb1, bg, bbe, 1.0f/(float)NE, bscale, bshift);
    k_bond_out   <<<dim3(NE/BROWS4),dim3(256),  0, stream>>>(efb, bpack, bb1, bscale, bshift, ba, bw2, bb2, out + NA*NATOM);
}

// Round 6
// 121.205 us; speedup vs baseline: 3.0312x; 1.1160x over previous
//
#include <hip/hip_runtime.h>
#include <math.h>

#define BG    128                      // graphs (B)
#define NN    40                       // nodes per graph
#define AK    32                       // K (mixture comps)
#define ZD    32                       // Z latent dim
#define HIDN  256                      // HID
#define ETAD  64                       // ETA
#define NATOM 24
#define NBOND 5
#define NA    (BG*NN)                  // 5120 nodes
#define EPG   (NN*(NN-1)/2)            // 780 edges per graph
#define NE    (BG*EPG)                 // 99840 edges
#define PP    257                      // padded LDS stride

typedef __attribute__((ext_vector_type(8))) short bf16x8;
typedef __attribute__((ext_vector_type(4))) float f32x4;

__device__ __forceinline__ unsigned short f2bf(float f) {
    union { float f; unsigned int u; } x; x.f = f;
    unsigned int r = x.u + 0x7fffu + ((x.u >> 16) & 1u);   // RNE
    return (unsigned short)(r >> 16);
}
__device__ __forceinline__ unsigned int pk2bf(float lo, float hi) {
    return (unsigned int)f2bf(lo) | ((unsigned int)f2bf(hi) << 16);
}

// ---------------- class head ----------------
__global__ void k_class_h1(const float* __restrict__ eta, const float* __restrict__ cw1,
                           const float* __restrict__ cb1, float* __restrict__ h1) {
    __shared__ float es[ETAD];
    int r = blockIdx.x, c = threadIdx.x;
    if (c < ETAD) es[c] = eta[r*ETAD + c];
    __syncthreads();
    float acc = cb1[c];
#pragma unroll
    for (int a = 0; a < ETAD; ++a) acc += es[a] * cw1[a*HIDN + c];
    h1[r*HIDN + c] = acc;
}

__global__ void k_class_stats(const float* __restrict__ h1, float* __restrict__ mean,
                              float* __restrict__ var) {
    int c = threadIdx.x;
    float s = 0.f;
    for (int r = 0; r < BG; ++r) s += h1[r*HIDN + c];
    float m = s / (float)BG;
    float v = 0.f;
    for (int r = 0; r < BG; ++r) { float d = h1[r*HIDN + c] - m; v += d*d; }
    mean[c] = m;
    var[c]  = v / (float)BG;
}

__global__ void k_class_out(const float* __restrict__ h1, const float* __restrict__ mean,
                            const float* __restrict__ var, const float* __restrict__ cg,
                            const float* __restrict__ cbe, const float* __restrict__ ca,
                            const float* __restrict__ cw2, const float* __restrict__ cb2,
                            float* __restrict__ log_pi) {
    __shared__ float p[HIDN];
    __shared__ float o[AK];
    int r = blockIdx.x, t = threadIdx.x;
    float a = ca[0];
    {
        float x = h1[r*HIDN + t];
        float m = mean[t], v = var[t];
        float xn = (x - m) * (1.0f/sqrtf(v + 1e-5f)) * cg[t] + cbe[t];
        p[t] = xn >= 0.f ? xn : a*xn;
    }
    __syncthreads();
    if (t < AK) {
        float acc = cb2[t];
        for (int c = 0; c < HIDN; ++c) acc += p[c] * cw2[c*AK + t];
        o[t] = acc;
    }
    __syncthreads();
    if (t < AK) {
        float m = -INFINITY;
#pragma unroll
        for (int k = 0; k < AK; ++k) m = fmaxf(m, o[k]);
        float S = 0.f;
#pragma unroll
        for (int k = 0; k < AK; ++k) S += expf(o[k] - m);
        log_pi[r*AK + t] = o[t] - m - logf(S);
    }
}

// ---------------- gumbel + latent z ----------------
__global__ void k_node_z(const float* __restrict__ log_pi, const float* __restrict__ gum,
                         const float* __restrict__ noise, const float* __restrict__ cm,
                         const float* __restrict__ cls, float* __restrict__ z) {
    int n = blockIdx.x*blockDim.x + threadIdx.x;
    if (n >= NA) return;
    int g = n / NN;
    float x[AK];
    float m = -INFINITY;
#pragma unroll
    for (int k = 0; k < AK; ++k) {
        float u  = gum[n*AK + k];
        float gk = -logf(-logf(u));
        float xk = log_pi[g*AK + k] + gk;     // TAU == 1.0
        x[k] = xk; m = fmaxf(m, xk);
    }
    float S = 0.f;
#pragma unroll
    for (int k = 0; k < AK; ++k) { float e = expf(x[k] - m); x[k] = e; S += e; }
    float best = -INFINITY; int am = 0;
#pragma unroll
    for (int k = 0; k < AK; ++k) { float s = x[k] / S; if (s > best) { best = s; am = k; } }
    float cam = (1.0f - best) + best;          // exact fp replication of y_hard - sg(y) + y
#pragma unroll
    for (int j = 0; j < ZD; ++j) {
        float ls = cam * cls[am*ZD + j];
        ls = fminf(fmaxf(ls, -20.0f), 30.0f);
        z[n*ZD + j] = noise[n*ZD + j] * expf(ls) + cam * cm[am*ZD + j];
    }
}

// ---------------- row moments via MFMA ----------------
__global__ __launch_bounds__(256) void k_moment(const float* __restrict__ src,
                                                float* __restrict__ mom, int nchunks) {
    __shared__ float sm[ZD*ZD + ZD];   // 1056 floats
    int t = threadIdx.x;
    for (int i = t; i < ZD*ZD + ZD; i += 256) sm[i] = 0.f;
    __syncthreads();
    int lane = t & 63, wv = t >> 6;
    int l15 = lane & 15, g4 = lane >> 4;
    int wgid = blockIdx.x * 4 + wv;
    int nw = gridDim.x * 4;
    f32x4 aII = {0,0,0,0}, aIJ = {0,0,0,0}, aJI = {0,0,0,0}, aJJ = {0,0,0,0};
    float mI = 0.f, mJ = 0.f;
    for (int ch = wgid; ch < nchunks; ch += nw) {
        const float* p = src + ((size_t)ch*32 + g4*8)*ZD + l15;
        float vI[8], vJ[8];
#pragma unroll
        for (int j = 0; j < 8; ++j) { vI[j] = p[j*ZD]; vJ[j] = p[j*ZD + 16]; }
        bf16x8 fI, fJ;
#pragma unroll
        for (int j = 0; j < 8; ++j) {
            fI[j] = (short)f2bf(vI[j]); fJ[j] = (short)f2bf(vJ[j]);
            mI += vI[j]; mJ += vJ[j];
        }
        aII = __builtin_amdgcn_mfma_f32_16x16x32_bf16(fI, fI, aII, 0, 0, 0);
        aIJ = __builtin_amdgcn_mfma_f32_16x16x32_bf16(fI, fJ, aIJ, 0, 0, 0);
        aJI = __builtin_amdgcn_mfma_f32_16x16x32_bf16(fJ, fI, aJI, 0, 0, 0);
        aJJ = __builtin_amdgcn_mfma_f32_16x16x32_bf16(fJ, fJ, aJJ, 0, 0, 0);
    }
#pragma unroll
    for (int r = 0; r < 4; ++r) {
        int row = g4*4 + r;
        atomicAdd(&sm[row*ZD + l15],             aII[r]);
        atomicAdd(&sm[row*ZD + 16 + l15],        aIJ[r]);
        atomicAdd(&sm[(16 + row)*ZD + l15],      aJI[r]);
        atomicAdd(&sm[(16 + row)*ZD + 16 + l15], aJJ[r]);
    }
    atomicAdd(&sm[ZD*ZD + l15], mI);
    atomicAdd(&sm[ZD*ZD + 16 + l15], mJ);
    __syncthreads();
    for (int i = t; i < ZD*ZD + ZD; i += 256) atomicAdd(&mom[i], sm[i]);
}

// ---------------- BN params from moments ----------------
__global__ __launch_bounds__(256) void k_prep(const float* __restrict__ mom,
                                              const float* __restrict__ w1,
                                              const float* __restrict__ b1,
                                              const float* __restrict__ g,
                                              const float* __restrict__ be,
                                              float inv_n,
                                              float* __restrict__ scale,
                                              float* __restrict__ shift) {
    __shared__ float mean[ZD];
    __shared__ float cov[ZD*ZD];
    __shared__ float vp[256], mp[256];
    int t = threadIdx.x;
    if (t < ZD) mean[t] = mom[ZD*ZD + t] * inv_n;
    __syncthreads();
    for (int pp = t; pp < ZD*ZD; pp += 256) {
        int a = pp >> 5, b = pp & 31;
        cov[pp] = mom[pp] * inv_n - mean[a]*mean[b];
    }
    __syncthreads();
    int c = blockIdx.x * 32 + (t & 31);
    int part = t >> 5;
    float wr[ZD];
#pragma unroll
    for (int b = 0; b < ZD; ++b) wr[b] = w1[b*HIDN + c];
    float var = 0.f, mh = 0.f;
#pragma unroll
    for (int q = 0; q < 4; ++q) {
        int a = part*4 + q;
        float tmp = 0.f;
#pragma unroll
        for (int b = 0; b < ZD; ++b) tmp += cov[a*ZD + b] * wr[b];
        var += tmp * wr[a];
        mh  += mean[a] * wr[a];
    }
    vp[t] = var; mp[t] = mh;
    __syncthreads();
    if (t < 32) {
        float v = 0.f, m = 0.f;
#pragma unroll
        for (int q = 0; q < 8; ++q) { v += vp[q*32 + t]; m += mp[q*32 + t]; }
        m += b1[c];
        float rs = rsqrtf(fmaxf(v, 0.f) + 1e-5f) * g[c];
        scale[c] = rs;
        shift[c] = be[c] - m * rs;
    }
}

// ---------------- fused atom MLP ----------------
#define AOR 8
__global__ __launch_bounds__(256) void k_atom_f(const float* __restrict__ z,
                                                const float* __restrict__ aw1,
                                                const float* __restrict__ ab1,
                                                const float* __restrict__ ascale,
                                                const float* __restrict__ ashift,
                                                const float* __restrict__ aa,
                                                const float* __restrict__ aw2,
                                                const float* __restrict__ ab2,
                                                float* __restrict__ out) {
    __shared__ float p[AOR*PP];
    __shared__ float aws[HIDN*NATOM];   // 24 KB
    int t = threadIdx.x;
    size_t r0 = (size_t)blockIdx.x * AOR;
    for (int i = t; i < HIDN*NATOM; i += 256) aws[i] = aw2[i];
    int c = t;
    float wreg[ZD];
#pragma unroll
    for (int a = 0; a < ZD; ++a) wreg[a] = aw1[a*HIDN + c];
    float sc = ascale[c];
    float shc = ashift[c] + ab1[c]*sc;
    float aP = aa[0];
    const float* zb = &z[r0*ZD];
#pragma unroll
    for (int r = 0; r < AOR; ++r) {
        float s = 0.f;
#pragma unroll
        for (int a = 0; a < ZD; ++a) s += zb[r*ZD + a] * wreg[a];
        float xn = s*sc + shc;
        p[r*PP + c] = xn >= 0.f ? xn : aP*xn;
    }
    __syncthreads();
    if (t < AOR*NATOM) {
        int r = t / NATOM, k = t % NATOM;
        float acc = ab2[k];
#pragma unroll 8
        for (int cc = 0; cc < HIDN; ++cc) acc += p[r*PP + cc] * aws[cc*NATOM + k];
        out[(r0 + r)*NATOM + k] = acc;
    }
}

// ---------------- pack symmetrized Wm into A-frag bf16 layout ----------------
// wp[d*1024 + Bt*512 + lane*8 + j] = bf16( Wsym[d][Bt*16 + (lane&15)][8*(lane>>4)+j] )
__global__ __launch_bounds__(256) void k_wmpack(const float* __restrict__ bm,
                                                unsigned short* __restrict__ wp) {
    int idx = blockIdx.x*256 + threadIdx.x;          // 32768 total
    int d = idx >> 10;
    int Bt = (idx >> 9) & 1, ln = (idx >> 3) & 63, j = idx & 7;
    int al = Bt*16 + (ln & 15);
    int be = (ln >> 4)*8 + j;
    float v = 0.5f * (bm[d*1024 + al*32 + be] + bm[d*1024 + be*32 + al]);
    wp[idx] = f2bf(v);
}

// ---------------- edge featurizer via MFMA (G = Z Wsym Z^T, symmetric) ----------------
// Block = (graph, dgroup of 8). 4 waves x 2 d each.
// Phase T': T'(b,i) tiles = mfma(Wsym_frag[Bt], Z_frag[I])  -> packed ds_write_b64
// Phase G : G(I,J) = mfma(Z_frag[I], T_frag[J]), upper-tri tiles, scatter to ef_lds.
__global__ __launch_bounds__(256) void k_edge_feat(const float* __restrict__ z,
                                                   const unsigned short* __restrict__ wmpk,
                                                   float* __restrict__ ef) {
    __shared__ unsigned short zfrag[3*512];     // 3 KB : Z A/B-frags, 3 row-tiles
    __shared__ unsigned short Tf[4][3*512];     // 12 KB: per-wave T frags
    __shared__ float efl[EPG*9];                // 28 KB: [e][dd] stride 9
    int t = threadIdx.x;
    int g = blockIdx.x >> 2, dg = blockIdx.x & 3;

    // stage zfrag[I][lane][j] = bf16(z[g][I*16 + (lane&15)][8*(lane>>4)+j])
    if (t < 192) {
        int I = t >> 6, ln = t & 63;
        int row = I*16 + (ln & 15), c0 = (ln >> 4)*8;
        unsigned int pk[4] = {0u, 0u, 0u, 0u};
        if (row < NN) {
            const float* zp = &z[((size_t)g*NN + row)*ZD + c0];
            float4 v0 = *(const float4*)zp;
            float4 v1 = *(const float4*)(zp + 4);
            pk[0] = pk2bf(v0.x, v0.y); pk[1] = pk2bf(v0.z, v0.w);
            pk[2] = pk2bf(v1.x, v1.y); pk[3] = pk2bf(v1.z, v1.w);
        }
        *(uint4*)&zfrag[(I*64 + ln)*8] = make_uint4(pk[0], pk[1], pk[2], pk[3]);
    }
    __syncthreads();

    int w = t >> 6, lane = t & 63;
    int l15 = lane & 15, gq = lane >> 4;
    f32x4 zero4 = {0.f, 0.f, 0.f, 0.f};

    bf16x8 zf[3];
#pragma unroll
    for (int I = 0; I < 3; ++I) zf[I] = *(const bf16x8*)&zfrag[I*512 + lane*8];

    for (int dk = 0; dk < 2; ++dk) {
        int dd = w*2 + dk;
        int d  = dg*8 + dd;
        // Wsym A-frags (global, L2-hot)
        bf16x8 wA[2];
        wA[0] = *(const bf16x8*)&wmpk[(d*2 + 0)*512 + lane*8];
        wA[1] = *(const bf16x8*)&wmpk[(d*2 + 1)*512 + lane*8];

        // phase T': D(Bt,I)[b'][i'] = T[I*16+l15(col)][Bt*16+4gq+r(row)]
        unsigned short* tw = &Tf[w][0];
        int gqp_lo = (gq >> 1);           // (4gq+r)>>3 within 16
        int jo     = (gq & 1)*4;          // (4gq)&7
#pragma unroll
        for (int Bt = 0; Bt < 2; ++Bt) {
#pragma unroll
            for (int I = 0; I < 3; ++I) {
                f32x4 c = __builtin_amdgcn_mfma_f32_16x16x32_bf16(wA[Bt], zf[I], zero4, 0, 0, 0);
                // store as T-frag: row=l15, k-slots (Bt*16+4gq)..+3
                int gqp = Bt*2 + gqp_lo;
                int pos = I*512 + gqp*128 + l15*8 + jo;     // halfword index
                unsigned int d0 = pk2bf(c[0], c[1]);
                unsigned int d1 = pk2bf(c[2], c[3]);
                *(uint2*)&tw[pos] = make_uint2(d0, d1);
            }
        }
        __syncthreads();   // Tf visible (also joins other waves, same count)

        bf16x8 tf[3];
#pragma unroll
        for (int J = 0; J < 3; ++J) tf[J] = *(const bf16x8*)&Tf[w][J*512 + lane*8];

        // phase G upper-tri tiles; scatter i<j entries
#pragma unroll
        for (int I = 0; I < 3; ++I) {
#pragma unroll
            for (int J = I; J < 3; ++J) {
                f32x4 gacc = __builtin_amdgcn_mfma_f32_16x16x32_bf16(zf[I], tf[J], zero4, 0, 0, 0);
                int j = J*16 + l15;
                if (j < NN) {
#pragma unroll
                    for (int r = 0; r < 4; ++r) {
                        int i = I*16 + 4*gq + r;
                        if (i < j) {
                            int e = i*(79 - i)/2 + (j - i - 1);
                            efl[e*9 + dd] = gacc[r];
                        }
                    }
                }
            }
        }
        __syncthreads();
    }

    // flush ef_lds -> global (32B per edge per block)
    size_t gE = (size_t)g * EPG;
    for (int idx = t; idx < EPG*8; idx += 256) {
        int e = idx >> 3, dd = idx & 7;
        ef[(gE + e)*ZD + dg*8 + dd] = efl[e*9 + dd];
    }
}

// ---------------- pack bw1 into per-lane-contiguous bf16 B-fragments ----------------
__global__ __launch_bounds__(256) void k_wpack(const float* __restrict__ bw1,
                                               unsigned short* __restrict__ bp) {
    int idx = blockIdx.x*256 + threadIdx.x;          // 8192 total
    int ct = idx >> 9, rem = idx & 511;
    int lane = rem >> 3, j = rem & 7;
    float v = bw1[((lane >> 4)*8 + j)*HIDN + ct*16 + (lane & 15)];
    bp[idx] = f2bf(v);
}

// ---------------- bond MLP: MFMA phase-1 + in-register phase-2 ----------------
#define BROWS4 64
__global__ __launch_bounds__(256) void k_bond_out(const float* __restrict__ ef,
                                                  const unsigned short* __restrict__ bpack,
                                                  const float* __restrict__ bb1,
                                                  const float* __restrict__ bscale,
                                                  const float* __restrict__ bshift,
                                                  const float* __restrict__ ba,
                                                  const float* __restrict__ bw2,
                                                  const float* __restrict__ bb2,
                                                  float* __restrict__ out) {
    __shared__ float w2s[HIDN*NBOND];    // 1280
    __shared__ float scs[HIDN];
    __shared__ float shs[HIDN];
    int t = threadIdx.x;
    size_t r0 = (size_t)blockIdx.x * BROWS4;

    for (int i = t; i < HIDN*NBOND; i += 256) w2s[i] = bw2[i];
    { float sc = bscale[t]; scs[t] = sc; shs[t] = bshift[t] + bb1[t]*sc; }
    __syncthreads();

    int lane = t & 63, w = t >> 6;
    int l15 = lane & 15, gq = lane >> 4;
    float aP = ba[0];
    float b2r[NBOND];
#pragma unroll
    for (int k = 0; k < NBOND; ++k) b2r[k] = bb2[k];

    const float* ar = &ef[(r0 + (size_t)w*16 + l15)*ZD + gq*8];
    float4 a0 = *(const float4*)ar;
    float4 a1 = *(const float4*)(ar + 4);
    bf16x8 af;
    af[0] = (short)f2bf(a0.x); af[1] = (short)f2bf(a0.y);
    af[2] = (short)f2bf(a0.z); af[3] = (short)f2bf(a0.w);
    af[4] = (short)f2bf(a1.x); af[5] = (short)f2bf(a1.y);
    af[6] = (short)f2bf(a1.z); af[7] = (short)f2bf(a1.w);

    float part[4][NBOND];
#pragma unroll
    for (int r = 0; r < 4; ++r)
#pragma unroll
        for (int k = 0; k < NBOND; ++k) part[r][k] = 0.f;

    f32x4 zero4 = {0.f, 0.f, 0.f, 0.f};
#pragma unroll
    for (int h = 0; h < 2; ++h) {
        bf16x8 bf[8];
#pragma unroll
        for (int q = 0; q < 8; ++q)
            bf[q] = *(const bf16x8*)&bpack[(h*8 + q)*512 + lane*8];
        f32x4 acc[8];
#pragma unroll
        for (int q = 0; q < 8; ++q)
            acc[q] = __builtin_amdgcn_mfma_f32_16x16x32_bf16(af, bf[q], zero4, 0, 0, 0);
#pragma unroll
        for (int q = 0; q < 8; ++q) {
            int c = (h*8 + q)*16 + l15;
            float sc = scs[c], sh = shs[c];
            float w0 = w2s[c*NBOND+0], w1v = w2s[c*NBOND+1], w2v = w2s[c*NBOND+2];
            float w3 = w2s[c*NBOND+3], w4 = w2s[c*NBOND+4];
#pragma unroll
            for (int r = 0; r < 4; ++r) {
                float xn = acc[q][r]*sc + sh;
                float pv = xn >= 0.f ? xn : aP*xn;
                part[r][0] += pv*w0; part[r][1] += pv*w1v; part[r][2] += pv*w2v;
                part[r][3] += pv*w3; part[r][4] += pv*w4;
            }
        }
    }

#pragma unroll
    for (int s = 1; s < 16; s <<= 1) {
#pragma unroll
        for (int r = 0; r < 4; ++r)
#pragma unroll
            for (int k = 0; k < NBOND; ++k)
                part[r][k] += __shfl_xor(part[r][k], s, 64);
    }

    if (l15 == 0) {
#pragma unroll
        for (int r = 0; r < 4; ++r) {
            size_t row = r0 + (size_t)w*16 + gq*4 + r;
            float lg[NBOND];
            float m = -INFINITY;
#pragma unroll
            for (int k = 0; k < NBOND; ++k) { lg[k] = part[r][k] + b2r[k]; m = fmaxf(m, lg[k]); }
            float S = 0.f;
#pragma unroll
            for (int k = 0; k < NBOND; ++k) { lg[k] = expf(lg[k] - m); S += lg[k]; }
            float invS = 1.f / S;
#pragma unroll
            for (int k = 0; k < NBOND; ++k) out[row*NBOND + k] = lg[k] * invS;
        }
    }
}

extern "C" void kernel_launch(void* const* d_in, const int* in_sizes, int n_in,
                              void* d_out, int out_size, void* d_ws, size_t ws_size,
                              hipStream_t stream) {
    (void)in_sizes; (void)n_in; (void)out_size; (void)ws_size;
    const float* eta  = (const float*)d_in[0];
    const float* gum  = (const float*)d_in[1];
    const float* noi  = (const float*)d_in[2];
    const float* cw1  = (const float*)d_in[5];
    const float* cb1  = (const float*)d_in[6];
    const float* cg   = (const float*)d_in[7];
    const float* cbe  = (const float*)d_in[8];
    const float* ca   = (const float*)d_in[9];
    const float* cw2  = (const float*)d_in[10];
    const float* cb2  = (const float*)d_in[11];
    const float* cm   = (const float*)d_in[12];
    const float* cls  = (const float*)d_in[13];
    const float* aw1  = (const float*)d_in[14];
    const float* ab1  = (const float*)d_in[15];
    const float* ag   = (const float*)d_in[16];
    const float* abe  = (const float*)d_in[17];
    const float* aa   = (const float*)d_in[18];
    const float* aw2  = (const float*)d_in[19];
    const float* ab2  = (const float*)d_in[20];
    const float* bm   = (const float*)d_in[21];
    const float* bw1  = (const float*)d_in[22];
    const float* bb1  = (const float*)d_in[23];
    const float* bg   = (const float*)d_in[24];
    const float* bbe  = (const float*)d_in[25];
    const float* ba   = (const float*)d_in[26];
    const float* bw2  = (const float*)d_in[27];
    const float* bb2  = (const float*)d_in[28];
    float* out = (float*)d_out;
    float* ws  = (float*)d_ws;

    // ws layout (floats)
    float*          mom_z  = ws;             // 1056
    float*          mom_ef = ws + 1056;      // 1056
    float*          ascale = ws + 2112;      // 256
    float*          ashift = ws + 2368;      // 256
    float*          bscale = ws + 2624;      // 256
    float*          bshift = ws + 2880;      // 256
    unsigned short* bpack  = (unsigned short*)(ws + 3136);   // 8192 ushort = 4096 floats
    unsigned short* wmpk   = (unsigned short*)(ws + 7232);   // 32768 ushort = 16384 floats
    float*          log_pi = ws + 23616;     // 4096
    float*          cmean  = ws + 27712;     // 256
    float*          cvar   = ws + 27968;     // 256
    float*          h1     = ws + 28224;     // 32768
    float*          zbuf   = ws + 60992;     // 163840
    float*          efb    = ws + 224832;    // 3194880   (total ~13.1 MiB)

    hipMemsetAsync(ws, 0, 2112*sizeof(float), stream);
    k_wpack      <<<dim3(32),       dim3(256),  0, stream>>>(bw1, bpack);
    k_wmpack     <<<dim3(128),      dim3(256),  0, stream>>>(bm, wmpk);
    k_class_h1   <<<dim3(BG),       dim3(HIDN), 0, stream>>>(eta, cw1, cb1, h1);
    k_class_stats<<<dim3(1),        dim3(HIDN), 0, stream>>>(h1, cmean, cvar);
    k_class_out  <<<dim3(BG),       dim3(HIDN), 0, stream>>>(h1, cmean, cvar, cg, cbe, ca, cw2, cb2, log_pi);
    k_node_z     <<<dim3(NA/256),   dim3(256),  0, stream>>>(log_pi, gum, noi, cm, cls, zbuf);
    k_moment     <<<dim3(40),       dim3(256),  0, stream>>>(zbuf, mom_z, NA/32);
    k_prep       <<<dim3(8),        dim3(256),  0, stream>>>(mom_z, aw1, ab1, ag, abe, 1.0f/(float)NA, ascale, ashift);
    k_atom_f     <<<dim3(NA/AOR),   dim3(256),  0, stream>>>(zbuf, aw1, ab1, ascale, ashift, aa, aw2, ab2, out);
    k_edge_feat  <<<dim3(4*BG),     dim3(256),  0, stream>>>(zbuf, wmpk, efb);
    k_moment     <<<dim3(195),      dim3(256),  0, stream>>>(efb, mom_ef, NE/32);
    k_prep       <<<dim3(8),        dim3(256),  0, stream>>>(mom_ef, bw1, bb1, bg, bbe, 1.0f/(float)NE, bscale, bshift);
    k_bond_out   <<<dim3(NE/BROWS4),dim3(256),  0, stream>>>(efb, bpack, bb1, bscale, bshift, ba, bw2, bb2, out + NA*NATOM);
}

// Round 7
// 104.904 us; speedup vs baseline: 3.5022x; 1.1554x over previous
//
#include <hip/hip_runtime.h>
#include <math.h>

#define BG    128                      // graphs (B)
#define NN    40                       // nodes per graph
#define AK    32                       // K (mixture comps)
#define ZD    32                       // Z latent dim
#define HIDN  256                      // HID
#define ETAD  64                       // ETA
#define NATOM 24
#define NBOND 5
#define NA    (BG*NN)                  // 5120 nodes
#define EPG   (NN*(NN-1)/2)            // 780 edges per graph
#define NE    (BG*EPG)                 // 99840 edges
#define PP    257                      // padded LDS stride

typedef __attribute__((ext_vector_type(8))) short bf16x8;
typedef __attribute__((ext_vector_type(4))) float f32x4;

__device__ __forceinline__ unsigned short f2bf(float f) {
    union { float f; unsigned int u; } x; x.f = f;
    unsigned int r = x.u + 0x7fffu + ((x.u >> 16) & 1u);   // RNE
    return (unsigned short)(r >> 16);
}
__device__ __forceinline__ unsigned int pk2bf(float lo, float hi) {
    return (unsigned int)f2bf(lo) | ((unsigned int)f2bf(hi) << 16);
}

// ---------------- fused setup: wmpack + wpack + zero accumulators ----------------
__global__ __launch_bounds__(256) void k_setup(const float* __restrict__ bm,
                                               const float* __restrict__ bw1,
                                               unsigned short* __restrict__ wmpk,
                                               unsigned short* __restrict__ bp,
                                               float* __restrict__ zacc) {
    int b = blockIdx.x, t = threadIdx.x;
    if (b < 128) {          // wmpack: symmetrized Wm -> A-frag bf16 layout (32768)
        int idx = b*256 + t;
        int d = idx >> 10;
        int Bt = (idx >> 9) & 1, ln = (idx >> 3) & 63, j = idx & 7;
        int al = Bt*16 + (ln & 15);
        int be = (ln >> 4)*8 + j;
        float v = 0.5f * (bm[d*1024 + al*32 + be] + bm[d*1024 + be*32 + al]);
        wmpk[idx] = f2bf(v);
    } else if (b < 160) {   // wpack: bw1 -> B-frag bf16 layout (8192)
        int idx = (b - 128)*256 + t;
        int ct = idx >> 9, rem = idx & 511;
        int lane = rem >> 3, j = rem & 7;
        float v = bw1[((lane >> 4)*8 + j)*HIDN + ct*16 + (lane & 15)];
        bp[idx] = f2bf(v);
    } else {                // zero mom_z + mom_ef + cstat = 2624 floats
        for (int i = t; i < 2624; i += 256) zacc[i] = 0.f;
    }
}

// ---------------- class hidden + column stats (fused) ----------------
__global__ __launch_bounds__(256) void k_class_h(const float* __restrict__ eta,
                                                 const float* __restrict__ cw1,
                                                 const float* __restrict__ cb1,
                                                 float* __restrict__ h1,
                                                 float* __restrict__ cstat) {
    __shared__ float es[16*ETAD];
    int b = blockIdx.x, t = threadIdx.x;
    int r0 = b*16;
    for (int i = t; i < 16*ETAD; i += 256) es[i] = eta[r0*ETAD + i];
    __syncthreads();
    int c = t;
    float bias = cb1[c], s = 0.f, ss = 0.f;
    for (int r = 0; r < 16; ++r) {
        float acc = bias;
#pragma unroll
        for (int a = 0; a < ETAD; ++a) acc += es[r*ETAD + a] * cw1[a*HIDN + c];
        h1[(r0 + r)*HIDN + c] = acc;
        s += acc; ss += acc*acc;
    }
    atomicAdd(&cstat[c], s);
    atomicAdd(&cstat[HIDN + c], ss);
}

// ---------------- class BN+W2+log_softmax + gumbel + z (fused, one block/graph) ----
__global__ __launch_bounds__(256) void k_class_z(const float* __restrict__ h1,
                                                 const float* __restrict__ cstat,
                                                 const float* __restrict__ cg,
                                                 const float* __restrict__ cbe,
                                                 const float* __restrict__ ca,
                                                 const float* __restrict__ cw2,
                                                 const float* __restrict__ cb2,
                                                 const float* __restrict__ gum,
                                                 const float* __restrict__ noise,
                                                 const float* __restrict__ cm,
                                                 const float* __restrict__ cls,
                                                 float* __restrict__ z) {
    __shared__ float p[HIDN];
    __shared__ float oo[AK];
    __shared__ float lp[AK];
    int g = blockIdx.x, t = threadIdx.x;
    float aP = ca[0];
    {
        float x = h1[g*HIDN + t];
        float m = cstat[t] * (1.0f/(float)BG);
        float v = cstat[HIDN + t] * (1.0f/(float)BG) - m*m;
        float xn = (x - m) * (1.0f/sqrtf(v + 1e-5f)) * cg[t] + cbe[t];
        p[t] = xn >= 0.f ? xn : aP*xn;
    }
    __syncthreads();
    if (t < AK) {
        float acc = cb2[t];
        for (int c = 0; c < HIDN; ++c) acc += p[c] * cw2[c*AK + t];
        oo[t] = acc;
    }
    __syncthreads();
    if (t < AK) {
        float m = -INFINITY;
#pragma unroll
        for (int k = 0; k < AK; ++k) m = fmaxf(m, oo[k]);
        float S = 0.f;
#pragma unroll
        for (int k = 0; k < AK; ++k) S += expf(oo[k] - m);
        lp[t] = oo[t] - m - logf(S);
    }
    __syncthreads();
    int lane = t & 31;
#pragma unroll
    for (int nb = 0; nb < 5; ++nb) {
        int node = nb*8 + (t >> 5);
        int n = g*NN + node;
        float u = gum[(size_t)n*AK + lane];
        float x = lp[lane] - logf(-logf(u));       // TAU == 1
        float m = x;
#pragma unroll
        for (int s = 1; s < 32; s <<= 1) m = fmaxf(m, __shfl_xor(m, s, 32));
        float e = expf(x - m);
        float S = e;
#pragma unroll
        for (int s = 1; s < 32; s <<= 1) S += __shfl_xor(S, s, 32);
        unsigned long long bal = __ballot(x == m);
        unsigned grp = (unsigned)(bal >> (t & 32));
        int am = __ffs(grp) - 1;
        float best = 1.0f / S;                     // y_soft at argmax (exp(0)=1)
        float cam = (1.0f - best) + best;          // exact fp replication
        float ls = cam * cls[am*ZD + lane];
        ls = fminf(fmaxf(ls, -20.0f), 30.0f);
        z[(size_t)n*ZD + lane] = noise[(size_t)n*ZD + lane]*expf(ls) + cam*cm[am*ZD + lane];
    }
}

// ---------------- row moments via MFMA ----------------
__global__ __launch_bounds__(256) void k_moment(const float* __restrict__ src,
                                                float* __restrict__ mom, int nchunks) {
    __shared__ float sm[ZD*ZD + ZD];   // 1056 floats
    int t = threadIdx.x;
    for (int i = t; i < ZD*ZD + ZD; i += 256) sm[i] = 0.f;
    __syncthreads();
    int lane = t & 63, wv = t >> 6;
    int l15 = lane & 15, g4 = lane >> 4;
    int wgid = blockIdx.x * 4 + wv;
    int nw = gridDim.x * 4;
    f32x4 aII = {0,0,0,0}, aIJ = {0,0,0,0}, aJI = {0,0,0,0}, aJJ = {0,0,0,0};
    float mI = 0.f, mJ = 0.f;
    for (int ch = wgid; ch < nchunks; ch += nw) {
        const float* p = src + ((size_t)ch*32 + g4*8)*ZD + l15;
        float vI[8], vJ[8];
#pragma unroll
        for (int j = 0; j < 8; ++j) { vI[j] = p[j*ZD]; vJ[j] = p[j*ZD + 16]; }
        bf16x8 fI, fJ;
#pragma unroll
        for (int j = 0; j < 8; ++j) {
            fI[j] = (short)f2bf(vI[j]); fJ[j] = (short)f2bf(vJ[j]);
            mI += vI[j]; mJ += vJ[j];
        }
        aII = __builtin_amdgcn_mfma_f32_16x16x32_bf16(fI, fI, aII, 0, 0, 0);
        aIJ = __builtin_amdgcn_mfma_f32_16x16x32_bf16(fI, fJ, aIJ, 0, 0, 0);
        aJI = __builtin_amdgcn_mfma_f32_16x16x32_bf16(fJ, fI, aJI, 0, 0, 0);
        aJJ = __builtin_amdgcn_mfma_f32_16x16x32_bf16(fJ, fJ, aJJ, 0, 0, 0);
    }
#pragma unroll
    for (int r = 0; r < 4; ++r) {
        int row = g4*4 + r;
        atomicAdd(&sm[row*ZD + l15],             aII[r]);
        atomicAdd(&sm[row*ZD + 16 + l15],        aIJ[r]);
        atomicAdd(&sm[(16 + row)*ZD + l15],      aJI[r]);
        atomicAdd(&sm[(16 + row)*ZD + 16 + l15], aJJ[r]);
    }
    atomicAdd(&sm[ZD*ZD + l15], mI);
    atomicAdd(&sm[ZD*ZD + 16 + l15], mJ);
    __syncthreads();
    for (int i = t; i < ZD*ZD + ZD; i += 256) atomicAdd(&mom[i], sm[i]);
}

// ---------------- BN params from moments (atom blocks 0-7, bond blocks 8-15) ------
__global__ __launch_bounds__(256) void k_prep2(const float* __restrict__ mom_z,
                                               const float* __restrict__ mom_ef,
                                               const float* __restrict__ aw1,
                                               const float* __restrict__ ab1,
                                               const float* __restrict__ ag,
                                               const float* __restrict__ abe,
                                               const float* __restrict__ bw1,
                                               const float* __restrict__ bb1,
                                               const float* __restrict__ bg,
                                               const float* __restrict__ bbe,
                                               float* __restrict__ ascale,
                                               float* __restrict__ ashift,
                                               float* __restrict__ bscale,
                                               float* __restrict__ bshift) {
    bool bond = blockIdx.x >= 8;
    const float* mom = bond ? mom_ef : mom_z;
    const float* w1  = bond ? bw1 : aw1;
    const float* b1  = bond ? bb1 : ab1;
    const float* g   = bond ? bg  : ag;
    const float* be  = bond ? bbe : abe;
    float inv_n      = bond ? (1.0f/(float)NE) : (1.0f/(float)NA);
    float* scale     = bond ? bscale : ascale;
    float* shift     = bond ? bshift : ashift;

    __shared__ float mean[ZD];
    __shared__ float cov[ZD*ZD];
    __shared__ float vp[256], mp[256];
    int t = threadIdx.x;
    if (t < ZD) mean[t] = mom[ZD*ZD + t] * inv_n;
    __syncthreads();
    for (int pp = t; pp < ZD*ZD; pp += 256) {
        int a = pp >> 5, b = pp & 31;
        cov[pp] = mom[pp] * inv_n - mean[a]*mean[b];
    }
    __syncthreads();
    int c = (blockIdx.x & 7) * 32 + (t & 31);
    int part = t >> 5;
    float wr[ZD];
#pragma unroll
    for (int b = 0; b < ZD; ++b) wr[b] = w1[b*HIDN + c];
    float var = 0.f, mh = 0.f;
#pragma unroll
    for (int q = 0; q < 4; ++q) {
        int a = part*4 + q;
        float tmp = 0.f;
#pragma unroll
        for (int b = 0; b < ZD; ++b) tmp += cov[a*ZD + b] * wr[b];
        var += tmp * wr[a];
        mh  += mean[a] * wr[a];
    }
    vp[t] = var; mp[t] = mh;
    __syncthreads();
    if (t < 32) {
        float v = 0.f, m = 0.f;
#pragma unroll
        for (int q = 0; q < 8; ++q) { v += vp[q*32 + t]; m += mp[q*32 + t]; }
        m += b1[c];
        float rs = rsqrtf(fmaxf(v, 0.f) + 1e-5f) * g[c];
        scale[c] = rs;
        shift[c] = be[c] - m * rs;
    }
}

// ---------------- fused atom MLP ----------------
#define AOR 8
__global__ __launch_bounds__(256) void k_atom_f(const float* __restrict__ z,
                                                const float* __restrict__ aw1,
                                                const float* __restrict__ ab1,
                                                const float* __restrict__ ascale,
                                                const float* __restrict__ ashift,
                                                const float* __restrict__ aa,
                                                const float* __restrict__ aw2,
                                                const float* __restrict__ ab2,
                                                float* __restrict__ out) {
    __shared__ float p[AOR*PP];
    __shared__ float aws[HIDN*NATOM];   // 24 KB
    int t = threadIdx.x;
    size_t r0 = (size_t)blockIdx.x * AOR;
    for (int i = t; i < HIDN*NATOM; i += 256) aws[i] = aw2[i];
    int c = t;
    float wreg[ZD];
#pragma unroll
    for (int a = 0; a < ZD; ++a) wreg[a] = aw1[a*HIDN + c];
    float sc = ascale[c];
    float shc = ashift[c] + ab1[c]*sc;
    float aP = aa[0];
    const float* zb = &z[r0*ZD];
#pragma unroll
    for (int r = 0; r < AOR; ++r) {
        float s = 0.f;
#pragma unroll
        for (int a = 0; a < ZD; ++a) s += zb[r*ZD + a] * wreg[a];
        float xn = s*sc + shc;
        p[r*PP + c] = xn >= 0.f ? xn : aP*xn;
    }
    __syncthreads();
    if (t < AOR*NATOM) {
        int r = t / NATOM, k = t % NATOM;
        float acc = ab2[k];
#pragma unroll 8
        for (int cc = 0; cc < HIDN; ++cc) acc += p[r*PP + cc] * aws[cc*NATOM + k];
        out[(r0 + r)*NATOM + k] = acc;
    }
}

// ---------------- edge featurizer via MFMA (G = Z Wsym Z^T, symmetric) ----------------
__global__ __launch_bounds__(256) void k_edge_feat(const float* __restrict__ z,
                                                   const unsigned short* __restrict__ wmpk,
                                                   float* __restrict__ ef) {
    __shared__ unsigned short zfrag[3*512];     // 3 KB
    __shared__ unsigned short Tf[4][3*512];     // 12 KB
    __shared__ float efl[EPG*9];                // 28 KB
    int t = threadIdx.x;
    int g = blockIdx.x >> 2, dg = blockIdx.x & 3;

    if (t < 192) {
        int I = t >> 6, ln = t & 63;
        int row = I*16 + (ln & 15), c0 = (ln >> 4)*8;
        unsigned int pk[4] = {0u, 0u, 0u, 0u};
        if (row < NN) {
            const float* zp = &z[((size_t)g*NN + row)*ZD + c0];
            float4 v0 = *(const float4*)zp;
            float4 v1 = *(const float4*)(zp + 4);
            pk[0] = pk2bf(v0.x, v0.y); pk[1] = pk2bf(v0.z, v0.w);
            pk[2] = pk2bf(v1.x, v1.y); pk[3] = pk2bf(v1.z, v1.w);
        }
        *(uint4*)&zfrag[(I*64 + ln)*8] = make_uint4(pk[0], pk[1], pk[2], pk[3]);
    }
    __syncthreads();

    int w = t >> 6, lane = t & 63;
    int l15 = lane & 15, gq = lane >> 4;
    f32x4 zero4 = {0.f, 0.f, 0.f, 0.f};

    bf16x8 zf[3];
#pragma unroll
    for (int I = 0; I < 3; ++I) zf[I] = *(const bf16x8*)&zfrag[I*512 + lane*8];

    for (int dk = 0; dk < 2; ++dk) {
        int dd = w*2 + dk;
        int d  = dg*8 + dd;
        bf16x8 wA[2];
        wA[0] = *(const bf16x8*)&wmpk[(d*2 + 0)*512 + lane*8];
        wA[1] = *(const bf16x8*)&wmpk[(d*2 + 1)*512 + lane*8];

        unsigned short* tw = &Tf[w][0];
        int gqp_lo = (gq >> 1);
        int jo     = (gq & 1)*4;
#pragma unroll
        for (int Bt = 0; Bt < 2; ++Bt) {
#pragma unroll
            for (int I = 0; I < 3; ++I) {
                f32x4 c = __builtin_amdgcn_mfma_f32_16x16x32_bf16(wA[Bt], zf[I], zero4, 0, 0, 0);
                int gqp = Bt*2 + gqp_lo;
                int pos = I*512 + gqp*128 + l15*8 + jo;
                unsigned int d0 = pk2bf(c[0], c[1]);
                unsigned int d1 = pk2bf(c[2], c[3]);
                *(uint2*)&tw[pos] = make_uint2(d0, d1);
            }
        }
        __syncthreads();

        bf16x8 tf[3];
#pragma unroll
        for (int J = 0; J < 3; ++J) tf[J] = *(const bf16x8*)&Tf[w][J*512 + lane*8];

#pragma unroll
        for (int I = 0; I < 3; ++I) {
#pragma unroll
            for (int J = I; J < 3; ++J) {
                f32x4 gacc = __builtin_amdgcn_mfma_f32_16x16x32_bf16(zf[I], tf[J], zero4, 0, 0, 0);
                int j = J*16 + l15;
                if (j < NN) {
#pragma unroll
                    for (int r = 0; r < 4; ++r) {
                        int i = I*16 + 4*gq + r;
                        if (i < j) {
                            int e = i*(79 - i)/2 + (j - i - 1);
                            efl[e*9 + dd] = gacc[r];
                        }
                    }
                }
            }
        }
        __syncthreads();
    }

    size_t gE = (size_t)g * EPG;
    for (int idx = t; idx < EPG*8; idx += 256) {
        int e = idx >> 3, dd = idx & 7;
        ef[(gE + e)*ZD + dg*8 + dd] = efl[e*9 + dd];
    }
}

// ---------------- bond MLP: MFMA phase-1 + in-register phase-2 ----------------
#define BROWS4 128
__global__ __launch_bounds__(256) void k_bond_out(const float* __restrict__ ef,
                                                  const unsigned short* __restrict__ bpack,
                                                  const float* __restrict__ bb1,
                                                  const float* __restrict__ bscale,
                                                  const float* __restrict__ bshift,
                                                  const float* __restrict__ ba,
                                                  const float* __restrict__ bw2,
                                                  const float* __restrict__ bb2,
                                                  float* __restrict__ out) {
    __shared__ float w2s[HIDN*NBOND];    // 1280
    __shared__ float scs[HIDN];
    __shared__ float shs[HIDN];
    int t = threadIdx.x;
    size_t r0 = (size_t)blockIdx.x * BROWS4;

    for (int i = t; i < HIDN*NBOND; i += 256) w2s[i] = bw2[i];
    { float sc = bscale[t]; scs[t] = sc; shs[t] = bshift[t] + bb1[t]*sc; }
    __syncthreads();

    int lane = t & 63, w = t >> 6;
    int l15 = lane & 15, gq = lane >> 4;
    float aP = ba[0];
    float b2r[NBOND];
#pragma unroll
    for (int k = 0; k < NBOND; ++k) b2r[k] = bb2[k];
    f32x4 zero4 = {0.f, 0.f, 0.f, 0.f};

#pragma unroll
    for (int rt = 0; rt < 2; ++rt) {
        size_t rowt = r0 + (size_t)(w*2 + rt)*16;
        const float* ar = &ef[(rowt + l15)*ZD + gq*8];
        float4 a0 = *(const float4*)ar;
        float4 a1 = *(const float4*)(ar + 4);
        bf16x8 af;
        af[0] = (short)f2bf(a0.x); af[1] = (short)f2bf(a0.y);
        af[2] = (short)f2bf(a0.z); af[3] = (short)f2bf(a0.w);
        af[4] = (short)f2bf(a1.x); af[5] = (short)f2bf(a1.y);
        af[6] = (short)f2bf(a1.z); af[7] = (short)f2bf(a1.w);

        float part[4][NBOND];
#pragma unroll
        for (int r = 0; r < 4; ++r)
#pragma unroll
            for (int k = 0; k < NBOND; ++k) part[r][k] = 0.f;

#pragma unroll
        for (int h = 0; h < 2; ++h) {
            bf16x8 bfr[8];
#pragma unroll
            for (int q = 0; q < 8; ++q)
                bfr[q] = *(const bf16x8*)&bpack[(h*8 + q)*512 + lane*8];
            f32x4 acc[8];
#pragma unroll
            for (int q = 0; q < 8; ++q)
                acc[q] = __builtin_amdgcn_mfma_f32_16x16x32_bf16(af, bfr[q], zero4, 0, 0, 0);
#pragma unroll
            for (int q = 0; q < 8; ++q) {
                int c = (h*8 + q)*16 + l15;
                float sc = scs[c], sh = shs[c];
                float w0 = w2s[c*NBOND+0], w1v = w2s[c*NBOND+1], w2v = w2s[c*NBOND+2];
                float w3 = w2s[c*NBOND+3], w4 = w2s[c*NBOND+4];
#pragma unroll
                for (int r = 0; r < 4; ++r) {
                    float xn = acc[q][r]*sc + sh;
                    float pv = xn >= 0.f ? xn : aP*xn;
                    part[r][0] += pv*w0; part[r][1] += pv*w1v; part[r][2] += pv*w2v;
                    part[r][3] += pv*w3; part[r][4] += pv*w4;
                }
            }
        }

#pragma unroll
        for (int s = 1; s < 16; s <<= 1) {
#pragma unroll
            for (int r = 0; r < 4; ++r)
#pragma unroll
                for (int k = 0; k < NBOND; ++k)
                    part[r][k] += __shfl_xor(part[r][k], s, 64);
        }

        if (l15 == 0) {
#pragma unroll
            for (int r = 0; r < 4; ++r) {
                size_t row = rowt + gq*4 + r;
                float lg[NBOND];
                float m = -INFINITY;
#pragma unroll
                for (int k = 0; k < NBOND; ++k) { lg[k] = part[r][k] + b2r[k]; m = fmaxf(m, lg[k]); }
                float S = 0.f;
#pragma unroll
                for (int k = 0; k < NBOND; ++k) { lg[k] = expf(lg[k] - m); S += lg[k]; }
                float invS = 1.f / S;
#pragma unroll
                for (int k = 0; k < NBOND; ++k) out[row*NBOND + k] = lg[k] * invS;
            }
        }
    }
}

extern "C" void kernel_launch(void* const* d_in, const int* in_sizes, int n_in,
                              void* d_out, int out_size, void* d_ws, size_t ws_size,
                              hipStream_t stream) {
    (void)in_sizes; (void)n_in; (void)out_size; (void)ws_size;
    const float* eta  = (const float*)d_in[0];
    const float* gum  = (const float*)d_in[1];
    const float* noi  = (const float*)d_in[2];
    const float* cw1  = (const float*)d_in[5];
    const float* cb1  = (const float*)d_in[6];
    const float* cg   = (const float*)d_in[7];
    const float* cbe  = (const float*)d_in[8];
    const float* ca   = (const float*)d_in[9];
    const float* cw2  = (const float*)d_in[10];
    const float* cb2  = (const float*)d_in[11];
    const float* cm   = (const float*)d_in[12];
    const float* cls  = (const float*)d_in[13];
    const float* aw1  = (const float*)d_in[14];
    const float* ab1  = (const float*)d_in[15];
    const float* ag   = (const float*)d_in[16];
    const float* abe  = (const float*)d_in[17];
    const float* aa   = (const float*)d_in[18];
    const float* aw2  = (const float*)d_in[19];
    const float* ab2  = (const float*)d_in[20];
    const float* bm   = (const float*)d_in[21];
    const float* bw1  = (const float*)d_in[22];
    const float* bb1  = (const float*)d_in[23];
    const float* bg   = (const float*)d_in[24];
    const float* bbe  = (const float*)d_in[25];
    const float* ba   = (const float*)d_in[26];
    const float* bw2  = (const float*)d_in[27];
    const float* bb2  = (const float*)d_in[28];
    float* out = (float*)d_out;
    float* ws  = (float*)d_ws;

    // ws layout (floats)
    float*          mom_z  = ws;             // 1056
    float*          mom_ef = ws + 1056;      // 1056
    float*          cstat  = ws + 2112;      // 512
    float*          ascale = ws + 2624;      // 256
    float*          ashift = ws + 2880;      // 256
    float*          bscale = ws + 3136;      // 256
    float*          bshift = ws + 3392;      // 256
    unsigned short* bpack  = (unsigned short*)(ws + 3648);   // 8192 ushort
    unsigned short* wmpk   = (unsigned short*)(ws + 7744);   // 32768 ushort
    float*          h1     = ws + 24128;     // 32768
    float*          zbuf   = ws + 56896;     // 163840
    float*          efb    = ws + 220736;    // 3194880   (total ~13.7 MiB)

    k_setup    <<<dim3(161),      dim3(256), 0, stream>>>(bm, bw1, wmpk, bpack, ws);
    k_class_h  <<<dim3(8),        dim3(256), 0, stream>>>(eta, cw1, cb1, h1, cstat);
    k_class_z  <<<dim3(BG),       dim3(256), 0, stream>>>(h1, cstat, cg, cbe, ca, cw2, cb2,
                                                          gum, noi, cm, cls, zbuf);
    k_moment   <<<dim3(40),       dim3(256), 0, stream>>>(zbuf, mom_z, NA/32);
    k_edge_feat<<<dim3(4*BG),     dim3(256), 0, stream>>>(zbuf, wmpk, efb);
    k_moment   <<<dim3(195),      dim3(256), 0, stream>>>(efb, mom_ef, NE/32);
    k_prep2    <<<dim3(16),       dim3(256), 0, stream>>>(mom_z, mom_ef, aw1, ab1, ag, abe,
                                                          bw1, bb1, bg, bbe,
                                                          ascale, ashift, bscale, bshift);
    k_atom_f   <<<dim3(NA/AOR),   dim3(256), 0, stream>>>(zbuf, aw1, ab1, ascale, ashift,
                                                          aa, aw2, ab2, out);
    k_bond_out <<<dim3(NE/BROWS4),dim3(256), 0, stream>>>(efb, bpack, bb1, bscale, bshift,
                                                          ba, bw2, bb2, out + NA*NATOM);
}